// Round 1
// baseline (1370.958 us; speedup 1.0000x reference)
//
#include <hip/hip_runtime.h>
#include <hip/hip_bf16.h>
#include <math.h>

#define L_SEQ   8192
#define E_DIM   512
#define NSTATE  16
#define NGRAPH  16

#define TILE 64
#define KT   16

__device__ __forceinline__ int lower_bound_dev(const int* __restrict__ a, int n, int v) {
    int lo = 0, hi = n;
    while (lo < hi) { int m = (lo + hi) >> 1; if (a[m] < v) lo = m + 1; else hi = m; }
    return lo;
}

// C[M,N] = A[M,K] * B[N,K]^T  (all row-major), TILE=64, 256 thr, 4x4/thread.
// EPI: 0 = store, 1 = +bias,leakyrelu, 2 = +bias,softplus, 3 = atomic segment-sum via index[m]
template<int EPI>
__global__ __launch_bounds__(256) void gemm_bt_kernel(
    const float* __restrict__ A, int lda,
    const float* __restrict__ B, int ldb,
    float* __restrict__ C, int ldc,
    int K,
    const float* __restrict__ bias,
    const int* __restrict__ index)
{
    __shared__ float As[TILE][KT + 1];
    __shared__ float Bs[TILE][KT + 1];
    const int tid = threadIdx.x;
    const int ty = tid >> 4, tx = tid & 15;
    const int m0 = blockIdx.y * TILE, n0 = blockIdx.x * TILE;
    const int lrow = tid >> 2;
    const int lk = (tid & 3) << 2;
    float acc[4][4] = {};

    for (int k0 = 0; k0 < K; k0 += KT) {
        float4 av = *(const float4*)(A + (size_t)(m0 + lrow) * lda + k0 + lk);
        float4 bv = *(const float4*)(B + (size_t)(n0 + lrow) * ldb + k0 + lk);
        As[lrow][lk + 0] = av.x; As[lrow][lk + 1] = av.y;
        As[lrow][lk + 2] = av.z; As[lrow][lk + 3] = av.w;
        Bs[lrow][lk + 0] = bv.x; Bs[lrow][lk + 1] = bv.y;
        Bs[lrow][lk + 2] = bv.z; Bs[lrow][lk + 3] = bv.w;
        __syncthreads();
        #pragma unroll
        for (int kk = 0; kk < KT; kk++) {
            float a[4], b[4];
            #pragma unroll
            for (int i = 0; i < 4; i++) a[i] = As[ty * 4 + i][kk];
            #pragma unroll
            for (int j = 0; j < 4; j++) b[j] = Bs[tx * 4 + j][kk];
            #pragma unroll
            for (int i = 0; i < 4; i++)
                #pragma unroll
                for (int j = 0; j < 4; j++)
                    acc[i][j] += a[i] * b[j];
        }
        __syncthreads();
    }

    #pragma unroll
    for (int i = 0; i < 4; i++) {
        const int m = m0 + ty * 4 + i;
        #pragma unroll
        for (int j = 0; j < 4; j++) {
            const int n = n0 + tx * 4 + j;
            float v = acc[i][j];
            if (EPI == 0) {
                C[(size_t)m * ldc + n] = v;
            } else if (EPI == 1) {
                v += bias[n];
                C[(size_t)m * ldc + n] = (v >= 0.f) ? v : 0.01f * v;
            } else if (EPI == 2) {
                v += bias[n];
                float sp = (v > 0.f) ? (v + log1pf(__expf(-v))) : log1pf(__expf(v));
                C[(size_t)m * ldc + n] = sp;
            } else {
                const int node = index[m];
                atomicAdd(&C[(size_t)node * ldc + n], v);
            }
        }
    }
}

// GEMM1: X[L,512] = leaky(cat(q,kv,ke)[L,1536] @ W[512,1536]^T + bias)
__global__ __launch_bounds__(256) void gemm1_kernel(
    const float* __restrict__ q, const float* __restrict__ kv, const float* __restrict__ ke,
    const float* __restrict__ W,
    const float* __restrict__ bias,
    float* __restrict__ X)
{
    __shared__ float As[TILE][KT + 1];
    __shared__ float Bs[TILE][KT + 1];
    const int tid = threadIdx.x;
    const int ty = tid >> 4, tx = tid & 15;
    const int m0 = blockIdx.y * TILE, n0 = blockIdx.x * TILE;
    const int lrow = tid >> 2;
    const int lk = (tid & 3) << 2;
    float acc[4][4] = {};

    for (int k0 = 0; k0 < 3 * E_DIM; k0 += KT) {
        const float* src = (k0 < E_DIM) ? q : ((k0 < 2 * E_DIM) ? kv : ke);
        const int col = k0 & (E_DIM - 1);
        float4 av = *(const float4*)(src + (size_t)(m0 + lrow) * E_DIM + col + lk);
        float4 bv = *(const float4*)(W + (size_t)(n0 + lrow) * (3 * E_DIM) + k0 + lk);
        As[lrow][lk + 0] = av.x; As[lrow][lk + 1] = av.y;
        As[lrow][lk + 2] = av.z; As[lrow][lk + 3] = av.w;
        Bs[lrow][lk + 0] = bv.x; Bs[lrow][lk + 1] = bv.y;
        Bs[lrow][lk + 2] = bv.z; Bs[lrow][lk + 3] = bv.w;
        __syncthreads();
        #pragma unroll
        for (int kk = 0; kk < KT; kk++) {
            float a[4], b[4];
            #pragma unroll
            for (int i = 0; i < 4; i++) a[i] = As[ty * 4 + i][kk];
            #pragma unroll
            for (int j = 0; j < 4; j++) b[j] = Bs[tx * 4 + j][kk];
            #pragma unroll
            for (int i = 0; i < 4; i++)
                #pragma unroll
                for (int j = 0; j < 4; j++)
                    acc[i][j] += a[i] * b[j];
        }
        __syncthreads();
    }

    #pragma unroll
    for (int i = 0; i < 4; i++) {
        const int m = m0 + ty * 4 + i;
        #pragma unroll
        for (int j = 0; j < 4; j++) {
            const int n = n0 + tx * 4 + j;
            float v = acc[i][j] + bias[n];
            X[(size_t)m * E_DIM + n] = (v >= 0.f) ? v : 0.01f * v;
        }
    }
}

// xc[t,c] = silu(conv_b[c] + sum_k conv_w[c,k]*x_in[t+k-3,c]*(seg match))
// x_in is xz[:, :512] with row stride 1024.
__global__ __launch_bounds__(256) void conv_kernel(
    const float* __restrict__ xz,
    const float* __restrict__ conv_w,
    const float* __restrict__ conv_b,
    const int* __restrict__ eb,
    float* __restrict__ xc)
{
    const int t = blockIdx.y;
    const int c = blockIdx.x * blockDim.x + threadIdx.x;
    const int ebt = eb[t];
    float acc = conv_b[c];
    #pragma unroll
    for (int k = 0; k < 4; k++) {
        const int j = t + k - 3;
        if (j >= 0 && eb[j] == ebt)
            acc += conv_w[c * 4 + k] * xz[(size_t)j * 1024 + c];
    }
    xc[(size_t)t * E_DIM + c] = acc / (1.f + __expf(-acc));
}

// Selective scan: one block per graph id, 512 threads = channels.
// h[c,s] = exp(delta*A[c,s])*h + delta*xc*B[t,s]; y = (h.C_t + D*xc)*silu(z)
__global__ __launch_bounds__(512) void scan_kernel(
    const float* __restrict__ delta,   // L x 512
    const float* __restrict__ xc,      // L x 512
    const float* __restrict__ xz,      // L x 1024 (z at col 512)
    const float* __restrict__ dbc,     // L x 64 (B at 32, C at 48)
    const float* __restrict__ A_log,   // 512 x 16
    const float* __restrict__ Dp,      // 512
    const int* __restrict__ eb,        // L
    float* __restrict__ y)             // L x 512
{
    const int g = blockIdx.x;
    const int c = threadIdx.x;
    const int start = lower_bound_dev(eb, L_SEQ, g);
    const int end   = lower_bound_dev(eb, L_SEQ, g + 1);
    if (start >= end) return;

    float Areg[NSTATE];
    #pragma unroll
    for (int s = 0; s < NSTATE; s++) Areg[s] = -__expf(A_log[c * NSTATE + s]);
    const float Dc = Dp[c];
    float h[NSTATE];
    #pragma unroll
    for (int s = 0; s < NSTATE; s++) h[s] = 0.f;

    __shared__ float bc[2][32];
    for (int t = start; t < end; t++) {
        const int buf = t & 1;
        if (c < 32) bc[buf][c] = dbc[(size_t)t * 64 + 32 + c];
        __syncthreads();
        const float dl  = delta[(size_t)t * E_DIM + c];
        const float xcv = xc[(size_t)t * E_DIM + c];
        const float zv  = xz[(size_t)t * 1024 + 512 + c];
        const float dx  = dl * xcv;
        float sum = 0.f;
        #pragma unroll
        for (int s = 0; s < NSTATE; s++) {
            const float dA = __expf(dl * Areg[s]);
            h[s] = h[s] * dA + dx * bc[buf][s];
            sum += h[s] * bc[buf][16 + s];
        }
        const float yv = sum + Dc * xcv;
        const float zs = zv / (1.f + __expf(-zv));
        y[(size_t)t * E_DIM + c] = yv * zs;
    }
}

extern "C" void kernel_launch(void* const* d_in, const int* in_sizes, int n_in,
                              void* d_out, int out_size, void* d_ws, size_t ws_size,
                              hipStream_t stream) {
    const float* q          = (const float*)d_in[0];
    const float* kv         = (const float*)d_in[1];
    const float* ke         = (const float*)d_in[2];
    const int*   index      = (const int*)d_in[3];
    const int*   eb         = (const int*)d_in[5];
    const float* w_weight   = (const float*)d_in[6];
    const float* w_bias     = (const float*)d_in[7];
    const float* in_proj_w  = (const float*)d_in[8];
    const float* conv_w     = (const float*)d_in[9];
    const float* conv_b     = (const float*)d_in[10];
    const float* x_proj_w   = (const float*)d_in[11];
    const float* dt_proj_w  = (const float*)d_in[12];
    const float* dt_proj_b  = (const float*)d_in[13];
    const float* A_log      = (const float*)d_in[14];
    const float* Dp         = (const float*)d_in[15];
    const float* out_proj_w = (const float*)d_in[16];
    float* out = (float*)d_out;

    float* ws    = (float*)d_ws;
    float* xz    = ws;                          // L*1024
    float* x     = xz + (size_t)L_SEQ * 1024;   // L*512 (reused as y)
    float* xc    = x  + (size_t)L_SEQ * 512;    // L*512
    float* dbc   = xc + (size_t)L_SEQ * 512;    // L*64
    float* delta = dbc + (size_t)L_SEQ * 64;    // L*512

    hipMemsetAsync(d_out, 0, (size_t)out_size * sizeof(float), stream);

    dim3 blk(256);
    // 1) x = leaky(cat(q,kv,ke) @ w_weight^T + w_bias)
    gemm1_kernel<<<dim3(E_DIM / TILE, L_SEQ / TILE), blk, 0, stream>>>(
        q, kv, ke, w_weight, w_bias, x);
    // 2) xz = x @ in_proj_w^T   (L x 1024)
    gemm_bt_kernel<0><<<dim3(1024 / TILE, L_SEQ / TILE), blk, 0, stream>>>(
        x, E_DIM, in_proj_w, E_DIM, xz, 1024, E_DIM, nullptr, nullptr);
    // 3) xc = silu(segconv(x_in))
    conv_kernel<<<dim3(E_DIM / 256, L_SEQ), blk, 0, stream>>>(xz, conv_w, conv_b, eb, xc);
    // 4) dbc = xc @ x_proj_w^T  (L x 64)
    gemm_bt_kernel<0><<<dim3(1, L_SEQ / TILE), blk, 0, stream>>>(
        xc, E_DIM, x_proj_w, E_DIM, dbc, 64, E_DIM, nullptr, nullptr);
    // 5) delta = softplus(dt @ dt_proj_w^T + dt_proj_b)  (dt = dbc[:, :32])
    gemm_bt_kernel<2><<<dim3(E_DIM / TILE, L_SEQ / TILE), blk, 0, stream>>>(
        dbc, 64, dt_proj_w, 32, delta, E_DIM, 32, dt_proj_b, nullptr);
    // 6) scan -> y (reuse x buffer)
    scan_kernel<<<dim3(NGRAPH), dim3(512), 0, stream>>>(
        delta, xc, xz, dbc, A_log, Dp, eb, x);
    // 7) out += segment_sum(y @ out_proj_w^T)
    gemm_bt_kernel<3><<<dim3(E_DIM / TILE, L_SEQ / TILE), blk, 0, stream>>>(
        x, E_DIM, out_proj_w, E_DIM, out, E_DIM, E_DIM, nullptr, index);
}

// Round 2
// 854.813 us; speedup vs baseline: 1.6038x; 1.6038x over previous
//
#include <hip/hip_runtime.h>
#include <hip/hip_bf16.h>
#include <math.h>

#define L_SEQ   8192
#define E_DIM   512
#define NSTATE  16
#define NGRAPH  16

#define TILE 64
#define KT   16

#define QCHUNK 32
#define NCHUNK (L_SEQ / QCHUNK)   // 256

// C[M,N] = A[M,K] * B[N,K]^T  (all row-major), TILE=64, 256 thr, 4x4/thread.
// EPI: 0 = store, 1 = +bias,leakyrelu, 2 = +bias,softplus, 3 = atomic segment-sum via index[m]
template<int EPI>
__global__ __launch_bounds__(256) void gemm_bt_kernel(
    const float* __restrict__ A, int lda,
    const float* __restrict__ B, int ldb,
    float* __restrict__ C, int ldc,
    int K,
    const float* __restrict__ bias,
    const int* __restrict__ index)
{
    __shared__ float As[TILE][KT + 1];
    __shared__ float Bs[TILE][KT + 1];
    const int tid = threadIdx.x;
    const int ty = tid >> 4, tx = tid & 15;
    const int m0 = blockIdx.y * TILE, n0 = blockIdx.x * TILE;
    const int lrow = tid >> 2;
    const int lk = (tid & 3) << 2;
    float acc[4][4] = {};

    for (int k0 = 0; k0 < K; k0 += KT) {
        float4 av = *(const float4*)(A + (size_t)(m0 + lrow) * lda + k0 + lk);
        float4 bv = *(const float4*)(B + (size_t)(n0 + lrow) * ldb + k0 + lk);
        As[lrow][lk + 0] = av.x; As[lrow][lk + 1] = av.y;
        As[lrow][lk + 2] = av.z; As[lrow][lk + 3] = av.w;
        Bs[lrow][lk + 0] = bv.x; Bs[lrow][lk + 1] = bv.y;
        Bs[lrow][lk + 2] = bv.z; Bs[lrow][lk + 3] = bv.w;
        __syncthreads();
        #pragma unroll
        for (int kk = 0; kk < KT; kk++) {
            float a[4], b[4];
            #pragma unroll
            for (int i = 0; i < 4; i++) a[i] = As[ty * 4 + i][kk];
            #pragma unroll
            for (int j = 0; j < 4; j++) b[j] = Bs[tx * 4 + j][kk];
            #pragma unroll
            for (int i = 0; i < 4; i++)
                #pragma unroll
                for (int j = 0; j < 4; j++)
                    acc[i][j] += a[i] * b[j];
        }
        __syncthreads();
    }

    #pragma unroll
    for (int i = 0; i < 4; i++) {
        const int m = m0 + ty * 4 + i;
        #pragma unroll
        for (int j = 0; j < 4; j++) {
            const int n = n0 + tx * 4 + j;
            float v = acc[i][j];
            if (EPI == 0) {
                C[(size_t)m * ldc + n] = v;
            } else if (EPI == 1) {
                v += bias[n];
                C[(size_t)m * ldc + n] = (v >= 0.f) ? v : 0.01f * v;
            } else if (EPI == 2) {
                v += bias[n];
                float sp = (v > 0.f) ? (v + log1pf(__expf(-v))) : log1pf(__expf(v));
                C[(size_t)m * ldc + n] = sp;
            } else {
                const int node = index[m];
                atomicAdd(&C[(size_t)node * ldc + n], v);
            }
        }
    }
}

// GEMM1: X[L,512] = leaky(cat(q,kv,ke)[L,1536] @ W[512,1536]^T + bias)
__global__ __launch_bounds__(256) void gemm1_kernel(
    const float* __restrict__ q, const float* __restrict__ kv, const float* __restrict__ ke,
    const float* __restrict__ W,
    const float* __restrict__ bias,
    float* __restrict__ X)
{
    __shared__ float As[TILE][KT + 1];
    __shared__ float Bs[TILE][KT + 1];
    const int tid = threadIdx.x;
    const int ty = tid >> 4, tx = tid & 15;
    const int m0 = blockIdx.y * TILE, n0 = blockIdx.x * TILE;
    const int lrow = tid >> 2;
    const int lk = (tid & 3) << 2;
    float acc[4][4] = {};

    for (int k0 = 0; k0 < 3 * E_DIM; k0 += KT) {
        const float* src = (k0 < E_DIM) ? q : ((k0 < 2 * E_DIM) ? kv : ke);
        const int col = k0 & (E_DIM - 1);
        float4 av = *(const float4*)(src + (size_t)(m0 + lrow) * E_DIM + col + lk);
        float4 bv = *(const float4*)(W + (size_t)(n0 + lrow) * (3 * E_DIM) + k0 + lk);
        As[lrow][lk + 0] = av.x; As[lrow][lk + 1] = av.y;
        As[lrow][lk + 2] = av.z; As[lrow][lk + 3] = av.w;
        Bs[lrow][lk + 0] = bv.x; Bs[lrow][lk + 1] = bv.y;
        Bs[lrow][lk + 2] = bv.z; Bs[lrow][lk + 3] = bv.w;
        __syncthreads();
        #pragma unroll
        for (int kk = 0; kk < KT; kk++) {
            float a[4], b[4];
            #pragma unroll
            for (int i = 0; i < 4; i++) a[i] = As[ty * 4 + i][kk];
            #pragma unroll
            for (int j = 0; j < 4; j++) b[j] = Bs[tx * 4 + j][kk];
            #pragma unroll
            for (int i = 0; i < 4; i++)
                #pragma unroll
                for (int j = 0; j < 4; j++)
                    acc[i][j] += a[i] * b[j];
        }
        __syncthreads();
    }

    #pragma unroll
    for (int i = 0; i < 4; i++) {
        const int m = m0 + ty * 4 + i;
        #pragma unroll
        for (int j = 0; j < 4; j++) {
            const int n = n0 + tx * 4 + j;
            float v = acc[i][j] + bias[n];
            X[(size_t)m * E_DIM + n] = (v >= 0.f) ? v : 0.01f * v;
        }
    }
}

// xc[t,c] = silu(conv_b[c] + sum_k conv_w[c,k]*x_in[t+k-3,c]*(seg match))
__global__ __launch_bounds__(256) void conv_kernel(
    const float* __restrict__ xz,
    const float* __restrict__ conv_w,
    const float* __restrict__ conv_b,
    const int* __restrict__ eb,
    float* __restrict__ xc)
{
    const int t = blockIdx.y;
    const int c = blockIdx.x * blockDim.x + threadIdx.x;
    const int ebt = eb[t];
    float acc = conv_b[c];
    #pragma unroll
    for (int k = 0; k < 4; k++) {
        const int j = t + k - 3;
        if (j >= 0 && eb[j] == ebt)
            acc += conv_w[c * 4 + k] * xz[(size_t)j * 1024 + c];
    }
    xc[(size_t)t * E_DIM + c] = acc / (1.f + __expf(-acc));
}

// ---------------- Chunked parallel selective scan ----------------
// Recurrence per (c,s): h[t] = a_t*h[t-1] + b_t, a_t = first[t] ? 0 : exp(dl*A),
// b_t = dl*xc*B[t,s]. Segment resets folded into a_t=0 -> plain linear scan.

// Pass 1: per-chunk local scan from h=0; emit aprod = prod(a), h_end.
// stats layout: [k][s][c] (s*512+c within chunk) for coalescing.
__global__ __launch_bounds__(512) void scan_chunk_local(
    const float* __restrict__ delta,
    const float* __restrict__ xc,
    const float* __restrict__ dbc,
    const float* __restrict__ A_log,
    const int* __restrict__ eb,
    float* __restrict__ stats_a,
    float* __restrict__ stats_h)
{
    const int k = blockIdx.x;
    const int c = threadIdx.x;
    const int t0 = k * QCHUNK;

    __shared__ float sBC[QCHUNK][32];
    __shared__ int sfirst[QCHUNK];
    for (int i = c; i < QCHUNK * 32; i += 512)
        sBC[i >> 5][i & 31] = dbc[(size_t)(t0 + (i >> 5)) * 64 + 32 + (i & 31)];
    if (c < QCHUNK) {
        const int t = t0 + c;
        sfirst[c] = (t == 0) || (eb[t] != eb[t - 1]);
    }
    __syncthreads();

    float Areg[NSTATE];
    #pragma unroll
    for (int s = 0; s < NSTATE; s++) Areg[s] = -__expf(A_log[c * NSTATE + s]);
    float h[NSTATE], ap[NSTATE];
    #pragma unroll
    for (int s = 0; s < NSTATE; s++) { h[s] = 0.f; ap[s] = 1.f; }

    for (int tt = 0; tt < QCHUNK; tt++) {
        const int t = t0 + tt;
        const float dl = delta[(size_t)t * E_DIM + c];
        const float dx = dl * xc[(size_t)t * E_DIM + c];
        const bool f = sfirst[tt];
        #pragma unroll
        for (int s = 0; s < NSTATE; s++) {
            const float a = f ? 0.f : __expf(dl * Areg[s]);
            ap[s] *= a;
            h[s] = a * h[s] + dx * sBC[tt][s];
        }
    }
    #pragma unroll
    for (int s = 0; s < NSTATE; s++) {
        const size_t o = ((size_t)k * NSTATE + s) * E_DIM + c;
        stats_a[o] = ap[s];
        stats_h[o] = h[s];
    }
}

// Pass 2: sequential combine over chunks; h_init[k] = state entering chunk k.
__global__ __launch_bounds__(256) void scan_chunk_combine(
    const float* __restrict__ stats_a,
    const float* __restrict__ stats_h,
    float* __restrict__ h_init)
{
    const int tid = blockIdx.x * 256 + threadIdx.x;   // 0..8191 = s*512+c
    float h = 0.f;
    #pragma unroll 4
    for (int k = 0; k < NCHUNK; k++) {
        const size_t o = (size_t)k * (E_DIM * NSTATE) + tid;
        h_init[o] = h;
        h = stats_a[o] * h + stats_h[o];
    }
}

// Pass 3: re-run local scan seeded with h_init, emit gated y.
__global__ __launch_bounds__(512) void scan_chunk_final(
    const float* __restrict__ delta,
    const float* __restrict__ xc,
    const float* __restrict__ xz,
    const float* __restrict__ dbc,
    const float* __restrict__ A_log,
    const float* __restrict__ Dp,
    const int* __restrict__ eb,
    const float* __restrict__ h_init,
    float* __restrict__ y)
{
    const int k = blockIdx.x;
    const int c = threadIdx.x;
    const int t0 = k * QCHUNK;

    __shared__ float sBC[QCHUNK][32];
    __shared__ int sfirst[QCHUNK];
    for (int i = c; i < QCHUNK * 32; i += 512)
        sBC[i >> 5][i & 31] = dbc[(size_t)(t0 + (i >> 5)) * 64 + 32 + (i & 31)];
    if (c < QCHUNK) {
        const int t = t0 + c;
        sfirst[c] = (t == 0) || (eb[t] != eb[t - 1]);
    }
    __syncthreads();

    float Areg[NSTATE];
    #pragma unroll
    for (int s = 0; s < NSTATE; s++) Areg[s] = -__expf(A_log[c * NSTATE + s]);
    const float Dc = Dp[c];
    float h[NSTATE];
    #pragma unroll
    for (int s = 0; s < NSTATE; s++)
        h[s] = h_init[(size_t)k * (E_DIM * NSTATE) + s * E_DIM + c];

    for (int tt = 0; tt < QCHUNK; tt++) {
        const int t = t0 + tt;
        const float dl  = delta[(size_t)t * E_DIM + c];
        const float xcv = xc[(size_t)t * E_DIM + c];
        const float zv  = xz[(size_t)t * 1024 + 512 + c];
        const float dx  = dl * xcv;
        const bool f = sfirst[tt];
        float sum = 0.f;
        #pragma unroll
        for (int s = 0; s < NSTATE; s++) {
            const float a = f ? 0.f : __expf(dl * Areg[s]);
            h[s] = a * h[s] + dx * sBC[tt][s];
            sum += h[s] * sBC[tt][16 + s];
        }
        const float yv = sum + Dc * xcv;
        const float zs = zv / (1.f + __expf(-zv));
        y[(size_t)t * E_DIM + c] = yv * zs;
    }
}

extern "C" void kernel_launch(void* const* d_in, const int* in_sizes, int n_in,
                              void* d_out, int out_size, void* d_ws, size_t ws_size,
                              hipStream_t stream) {
    const float* q          = (const float*)d_in[0];
    const float* kv         = (const float*)d_in[1];
    const float* ke         = (const float*)d_in[2];
    const int*   index      = (const int*)d_in[3];
    const int*   eb         = (const int*)d_in[5];
    const float* w_weight   = (const float*)d_in[6];
    const float* w_bias     = (const float*)d_in[7];
    const float* in_proj_w  = (const float*)d_in[8];
    const float* conv_w     = (const float*)d_in[9];
    const float* conv_b     = (const float*)d_in[10];
    const float* x_proj_w   = (const float*)d_in[11];
    const float* dt_proj_w  = (const float*)d_in[12];
    const float* dt_proj_b  = (const float*)d_in[13];
    const float* A_log      = (const float*)d_in[14];
    const float* Dp         = (const float*)d_in[15];
    const float* out_proj_w = (const float*)d_in[16];
    float* out = (float*)d_out;

    float* ws    = (float*)d_ws;
    float* xz    = ws;                          // L*1024
    float* x     = xz + (size_t)L_SEQ * 1024;   // L*512 (reused: chunk stats, then y)
    float* xc    = x  + (size_t)L_SEQ * 512;    // L*512
    float* dbc   = xc + (size_t)L_SEQ * 512;    // L*64
    float* delta = dbc + (size_t)L_SEQ * 64;    // L*512
    float* h_init = delta + (size_t)L_SEQ * 512; // NCHUNK*8192 = 2M floats

    // stats alias the x/y buffer (x is dead after gemm2 consumes it... careful:
    // x is consumed by gemm2 before the scan; y written in pass 3 overwrites stats,
    // which are only needed by pass 2).
    float* stats_a = x;                               // NCHUNK*8192
    float* stats_h = x + (size_t)NCHUNK * E_DIM * NSTATE;

    hipMemsetAsync(d_out, 0, (size_t)out_size * sizeof(float), stream);

    dim3 blk(256);
    // 1) x = leaky(cat(q,kv,ke) @ w_weight^T + w_bias)
    gemm1_kernel<<<dim3(E_DIM / TILE, L_SEQ / TILE), blk, 0, stream>>>(
        q, kv, ke, w_weight, w_bias, x);
    // 2) xz = x @ in_proj_w^T   (L x 1024)
    gemm_bt_kernel<0><<<dim3(1024 / TILE, L_SEQ / TILE), blk, 0, stream>>>(
        x, E_DIM, in_proj_w, E_DIM, xz, 1024, E_DIM, nullptr, nullptr);
    // 3) xc = silu(segconv(x_in))
    conv_kernel<<<dim3(E_DIM / 256, L_SEQ), blk, 0, stream>>>(xz, conv_w, conv_b, eb, xc);
    // 4) dbc = xc @ x_proj_w^T  (L x 64)
    gemm_bt_kernel<0><<<dim3(1, L_SEQ / TILE), blk, 0, stream>>>(
        xc, E_DIM, x_proj_w, E_DIM, dbc, 64, E_DIM, nullptr, nullptr);
    // 5) delta = softplus(dt @ dt_proj_w^T + dt_proj_b)
    gemm_bt_kernel<2><<<dim3(E_DIM / TILE, L_SEQ / TILE), blk, 0, stream>>>(
        dbc, 64, dt_proj_w, 32, delta, E_DIM, 32, dt_proj_b, nullptr);
    // 6) chunked parallel scan -> y (in x buffer)
    scan_chunk_local<<<dim3(NCHUNK), dim3(512), 0, stream>>>(
        delta, xc, dbc, A_log, eb, stats_a, stats_h);
    scan_chunk_combine<<<dim3(8192 / 256), blk, 0, stream>>>(
        stats_a, stats_h, h_init);
    scan_chunk_final<<<dim3(NCHUNK), dim3(512), 0, stream>>>(
        delta, xc, xz, dbc, A_log, Dp, eb, h_init, x);
    // 7) out += segment_sum(y @ out_proj_w^T)
    gemm_bt_kernel<3><<<dim3(E_DIM / TILE, L_SEQ / TILE), blk, 0, stream>>>(
        x, E_DIM, out_proj_w, E_DIM, out, E_DIM, E_DIM, nullptr, index);
}

// Round 3
// 436.086 us; speedup vs baseline: 3.1438x; 1.9602x over previous
//
#include <hip/hip_runtime.h>
#include <hip/hip_bf16.h>
#include <math.h>

#define L_SEQ   8192
#define E_DIM   512
#define NSTATE  16
#define NGRAPH  16

#define TILE 64
#define KT   16

#define QCHUNK 64
#define NCHUNK (L_SEQ / QCHUNK)   // 128

typedef unsigned short u16;
typedef __attribute__((ext_vector_type(8))) short short8;
typedef __attribute__((ext_vector_type(4))) float floatx4;

__device__ __forceinline__ u16 f2bf(float f) {
    union { float f; unsigned u; } in; in.f = f;
    unsigned u = in.u;
    u += 0x7FFFu + ((u >> 16) & 1u);   // RNE
    return (u16)(u >> 16);
}

__device__ __forceinline__ void gl2lds16(const void* g, void* l) {
    __builtin_amdgcn_global_load_lds(
        (const __attribute__((address_space(1))) void*)g,
        (__attribute__((address_space(3))) void*)l, 16, 0, 0);
}

// convert 8 consecutive f32 -> 8 bf16, write 16B to LDS
__device__ __forceinline__ void stage_cvt8(const float* __restrict__ g, u16* lds) {
    const float4 a = *(const float4*)g;
    const float4 b = *(const float4*)(g + 4);
    union { short8 v; u16 u[8]; } t;
    t.u[0] = f2bf(a.x); t.u[1] = f2bf(a.y); t.u[2] = f2bf(a.z); t.u[3] = f2bf(a.w);
    t.u[4] = f2bf(b.x); t.u[5] = f2bf(b.y); t.u[6] = f2bf(b.z); t.u[7] = f2bf(b.w);
    *(short8*)lds = t.v;
}

// ---------------- MFMA GEMM (bf16 inputs in HBM), 128x128 tile ----------------
// C[M,N] = A[M,K] * B[N,K]^T. A,B bf16; C f32.
// EPI 0: plain f32 store. EPI 1: atomicAdd into C[index[m]][n] (segment sum).
template<int EPI>
__global__ __launch_bounds__(256) void gemm_bf16_mfma_kernel(
    const u16* __restrict__ A, int lda,
    const u16* __restrict__ B, int ldb,
    float* __restrict__ C, int ldc, int K,
    const int* __restrict__ index)
{
    __shared__ __align__(16) u16 As[128 * 32];
    __shared__ __align__(16) u16 Bs[128 * 32];
    const int tid  = threadIdx.x;
    const int lane = tid & 63;
    const int wave = tid >> 6;
    const int m0 = blockIdx.y * 128, n0 = blockIdx.x * 128;
    const int wm = (wave >> 1) * 64, wn = (wave & 1) * 64;
    const int ar0 = tid >> 2;            // chunk row (0..63)
    const int ak  = (tid & 3) * 8;       // chunk k offset

    const u16* pa0 = A + (size_t)(m0 + ar0) * lda + ak;
    const u16* pa1 = pa0 + (size_t)64 * lda;
    const u16* pb0 = B + (size_t)(n0 + ar0) * ldb + ak;
    const u16* pb1 = pb0 + (size_t)64 * ldb;
    u16* la0 = As + wave * 512;          // HW adds lane*16B
    u16* la1 = As + 2048 + wave * 512;
    u16* lb0 = Bs + wave * 512;
    u16* lb1 = Bs + 2048 + wave * 512;

    floatx4 acc[4][4] = {};
    const int r16 = lane & 15, kh = lane >> 4;

    for (int k0 = 0; k0 < K; k0 += 32) {
        gl2lds16(pa0 + k0, la0);
        gl2lds16(pa1 + k0, la1);
        gl2lds16(pb0 + k0, lb0);
        gl2lds16(pb1 + k0, lb1);
        __syncthreads();
        short8 af[4], bfr[4];
        #pragma unroll
        for (int i = 0; i < 4; i++) {
            af[i]  = *(const short8*)(As + (wm + i * 16 + r16) * 32 + kh * 8);
            bfr[i] = *(const short8*)(Bs + (wn + i * 16 + r16) * 32 + kh * 8);
        }
        #pragma unroll
        for (int i = 0; i < 4; i++)
            #pragma unroll
            for (int j = 0; j < 4; j++)
                acc[i][j] = __builtin_amdgcn_mfma_f32_16x16x32_bf16(af[i], bfr[j], acc[i][j], 0, 0, 0);
        __syncthreads();
    }

    #pragma unroll
    for (int i = 0; i < 4; i++) {
        #pragma unroll
        for (int r = 0; r < 4; r++) {
            const int m = m0 + wm + i * 16 + kh * 4 + r;
            #pragma unroll
            for (int j = 0; j < 4; j++) {
                const int n = n0 + wn + j * 16 + r16;
                const float v = acc[i][j][r];
                if (EPI == 0) {
                    C[(size_t)m * ldc + n] = v;
                } else {
                    atomicAdd(&C[(size_t)index[m] * ldc + n], v);
                }
            }
        }
    }
}

// GEMM1: Xb[L,512](bf16) = leaky(cat(q,kv,ke)[L,1536] @ W[512,1536]^T + bias)
// f32 sources converted in-register during staging.
__global__ __launch_bounds__(256) void gemm1_mfma_kernel(
    const float* __restrict__ q, const float* __restrict__ kv, const float* __restrict__ ke,
    const float* __restrict__ W,
    const float* __restrict__ bias,
    u16* __restrict__ Xb)
{
    __shared__ __align__(16) u16 As[128 * 32];
    __shared__ __align__(16) u16 Bs[128 * 32];
    const int tid  = threadIdx.x;
    const int lane = tid & 63;
    const int wave = tid >> 6;
    const int m0 = blockIdx.y * 128, n0 = blockIdx.x * 128;
    const int wm = (wave >> 1) * 64, wn = (wave & 1) * 64;
    const int ar0 = tid >> 2;
    const int ar1 = ar0 + 64;
    const int ak  = (tid & 3) * 8;

    floatx4 acc[4][4] = {};
    const int r16 = lane & 15, kh = lane >> 4;

    for (int k0 = 0; k0 < 3 * E_DIM; k0 += 32) {
        const int kg = k0 + ak;
        const float* asrc = (kg < 512) ? q : ((kg < 1024) ? kv : ke);
        const int acol = kg & 511;
        stage_cvt8(asrc + (size_t)(m0 + ar0) * 512 + acol, As + tid * 8);
        stage_cvt8(asrc + (size_t)(m0 + ar1) * 512 + acol, As + 2048 + tid * 8);
        stage_cvt8(W + (size_t)(n0 + ar0) * 1536 + kg, Bs + tid * 8);
        stage_cvt8(W + (size_t)(n0 + ar1) * 1536 + kg, Bs + 2048 + tid * 8);
        __syncthreads();
        short8 af[4], bfr[4];
        #pragma unroll
        for (int i = 0; i < 4; i++) {
            af[i]  = *(const short8*)(As + (wm + i * 16 + r16) * 32 + kh * 8);
            bfr[i] = *(const short8*)(Bs + (wn + i * 16 + r16) * 32 + kh * 8);
        }
        #pragma unroll
        for (int i = 0; i < 4; i++)
            #pragma unroll
            for (int j = 0; j < 4; j++)
                acc[i][j] = __builtin_amdgcn_mfma_f32_16x16x32_bf16(af[i], bfr[j], acc[i][j], 0, 0, 0);
        __syncthreads();
    }

    #pragma unroll
    for (int i = 0; i < 4; i++) {
        #pragma unroll
        for (int r = 0; r < 4; r++) {
            const int m = m0 + wm + i * 16 + kh * 4 + r;
            #pragma unroll
            for (int j = 0; j < 4; j++) {
                const int n = n0 + wn + j * 16 + r16;
                float v = acc[i][j][r] + bias[n];
                v = (v >= 0.f) ? v : 0.01f * v;
                Xb[(size_t)m * 512 + n] = f2bf(v);
            }
        }
    }
}

// f32 -> bf16 bulk cast (n4 = n/4)
__global__ __launch_bounds__(256) void cast_bf16_kernel(
    const float* __restrict__ s, u16* __restrict__ d, int n4)
{
    const int i = blockIdx.x * 256 + threadIdx.x;
    if (i >= n4) return;
    const float4 v = ((const float4*)s)[i];
    ushort4 u;
    u.x = f2bf(v.x); u.y = f2bf(v.y); u.z = f2bf(v.z); u.w = f2bf(v.w);
    ((ushort4*)d)[i] = u;
}

// ---------------- f32 tile GEMM for the two small GEMMs ----------------
// EPI: 0 = store, 2 = +bias,softplus
template<int EPI>
__global__ __launch_bounds__(256) void gemm_bt_kernel(
    const float* __restrict__ A, int lda,
    const float* __restrict__ B, int ldb,
    float* __restrict__ C, int ldc,
    int K,
    const float* __restrict__ bias)
{
    __shared__ float As[TILE][KT + 1];
    __shared__ float Bs[TILE][KT + 1];
    const int tid = threadIdx.x;
    const int ty = tid >> 4, tx = tid & 15;
    const int m0 = blockIdx.y * TILE, n0 = blockIdx.x * TILE;
    const int lrow = tid >> 2;
    const int lk = (tid & 3) << 2;
    float acc[4][4] = {};

    for (int k0 = 0; k0 < K; k0 += KT) {
        float4 av = *(const float4*)(A + (size_t)(m0 + lrow) * lda + k0 + lk);
        float4 bv = *(const float4*)(B + (size_t)(n0 + lrow) * ldb + k0 + lk);
        As[lrow][lk + 0] = av.x; As[lrow][lk + 1] = av.y;
        As[lrow][lk + 2] = av.z; As[lrow][lk + 3] = av.w;
        Bs[lrow][lk + 0] = bv.x; Bs[lrow][lk + 1] = bv.y;
        Bs[lrow][lk + 2] = bv.z; Bs[lrow][lk + 3] = bv.w;
        __syncthreads();
        #pragma unroll
        for (int kk = 0; kk < KT; kk++) {
            float a[4], b[4];
            #pragma unroll
            for (int i = 0; i < 4; i++) a[i] = As[ty * 4 + i][kk];
            #pragma unroll
            for (int j = 0; j < 4; j++) b[j] = Bs[tx * 4 + j][kk];
            #pragma unroll
            for (int i = 0; i < 4; i++)
                #pragma unroll
                for (int j = 0; j < 4; j++)
                    acc[i][j] += a[i] * b[j];
        }
        __syncthreads();
    }

    #pragma unroll
    for (int i = 0; i < 4; i++) {
        const int m = m0 + ty * 4 + i;
        #pragma unroll
        for (int j = 0; j < 4; j++) {
            const int n = n0 + tx * 4 + j;
            float v = acc[i][j];
            if (EPI == 0) {
                C[(size_t)m * ldc + n] = v;
            } else {
                v += bias[n];
                float sp = (v > 0.f) ? (v + log1pf(__expf(-v))) : log1pf(__expf(v));
                C[(size_t)m * ldc + n] = sp;
            }
        }
    }
}

// xc[t,c] = silu(conv_b[c] + sum_k conv_w[c,k]*x_in[t+k-3,c]*(seg match))
__global__ __launch_bounds__(256) void conv_kernel(
    const float* __restrict__ xz,
    const float* __restrict__ conv_w,
    const float* __restrict__ conv_b,
    const int* __restrict__ eb,
    float* __restrict__ xc)
{
    const int t = blockIdx.y;
    const int c = blockIdx.x * blockDim.x + threadIdx.x;
    const int ebt = eb[t];
    float acc = conv_b[c];
    #pragma unroll
    for (int k = 0; k < 4; k++) {
        const int j = t + k - 3;
        if (j >= 0 && eb[j] == ebt)
            acc += conv_w[c * 4 + k] * xz[(size_t)j * 1024 + c];
    }
    xc[(size_t)t * E_DIM + c] = acc / (1.f + __expf(-acc));
}

// ---------------- Chunked parallel selective scan ----------------
__global__ __launch_bounds__(512) void scan_chunk_local(
    const float* __restrict__ delta,
    const float* __restrict__ xc,
    const float* __restrict__ dbc,
    const float* __restrict__ A_log,
    const int* __restrict__ eb,
    float* __restrict__ stats_a,
    float* __restrict__ stats_h)
{
    const int k = blockIdx.x;
    const int c = threadIdx.x;
    const int t0 = k * QCHUNK;

    __shared__ float sBC[QCHUNK][32];
    __shared__ int sfirst[QCHUNK];
    for (int i = c; i < QCHUNK * 32; i += 512)
        sBC[i >> 5][i & 31] = dbc[(size_t)(t0 + (i >> 5)) * 64 + 32 + (i & 31)];
    if (c < QCHUNK) {
        const int t = t0 + c;
        sfirst[c] = (t == 0) || (eb[t] != eb[t - 1]);
    }
    __syncthreads();

    float Areg[NSTATE];
    #pragma unroll
    for (int s = 0; s < NSTATE; s++) Areg[s] = -__expf(A_log[c * NSTATE + s]);
    float h[NSTATE], ap[NSTATE];
    #pragma unroll
    for (int s = 0; s < NSTATE; s++) { h[s] = 0.f; ap[s] = 1.f; }

    for (int tt = 0; tt < QCHUNK; tt++) {
        const int t = t0 + tt;
        const float dl = delta[(size_t)t * E_DIM + c];
        const float dx = dl * xc[(size_t)t * E_DIM + c];
        const bool f = sfirst[tt];
        #pragma unroll
        for (int s = 0; s < NSTATE; s++) {
            const float a = f ? 0.f : __expf(dl * Areg[s]);
            ap[s] *= a;
            h[s] = a * h[s] + dx * sBC[tt][s];
        }
    }
    #pragma unroll
    for (int s = 0; s < NSTATE; s++) {
        const size_t o = ((size_t)k * NSTATE + s) * E_DIM + c;
        stats_a[o] = ap[s];
        stats_h[o] = h[s];
    }
}

__global__ __launch_bounds__(256) void scan_chunk_combine(
    const float* __restrict__ stats_a,
    const float* __restrict__ stats_h,
    float* __restrict__ h_init)
{
    const int tid = blockIdx.x * 256 + threadIdx.x;   // 0..8191
    float h = 0.f;
    #pragma unroll 4
    for (int k = 0; k < NCHUNK; k++) {
        const size_t o = (size_t)k * (E_DIM * NSTATE) + tid;
        h_init[o] = h;
        h = stats_a[o] * h + stats_h[o];
    }
}

__global__ __launch_bounds__(512) void scan_chunk_final(
    const float* __restrict__ delta,
    const float* __restrict__ xc,
    const float* __restrict__ xz,
    const float* __restrict__ dbc,
    const float* __restrict__ A_log,
    const float* __restrict__ Dp,
    const int* __restrict__ eb,
    const float* __restrict__ h_init,
    u16* __restrict__ yb)
{
    const int k = blockIdx.x;
    const int c = threadIdx.x;
    const int t0 = k * QCHUNK;

    __shared__ float sBC[QCHUNK][32];
    __shared__ int sfirst[QCHUNK];
    for (int i = c; i < QCHUNK * 32; i += 512)
        sBC[i >> 5][i & 31] = dbc[(size_t)(t0 + (i >> 5)) * 64 + 32 + (i & 31)];
    if (c < QCHUNK) {
        const int t = t0 + c;
        sfirst[c] = (t == 0) || (eb[t] != eb[t - 1]);
    }
    __syncthreads();

    float Areg[NSTATE];
    #pragma unroll
    for (int s = 0; s < NSTATE; s++) Areg[s] = -__expf(A_log[c * NSTATE + s]);
    const float Dc = Dp[c];
    float h[NSTATE];
    #pragma unroll
    for (int s = 0; s < NSTATE; s++)
        h[s] = h_init[(size_t)k * (E_DIM * NSTATE) + s * E_DIM + c];

    for (int tt = 0; tt < QCHUNK; tt++) {
        const int t = t0 + tt;
        const float dl  = delta[(size_t)t * E_DIM + c];
        const float xcv = xc[(size_t)t * E_DIM + c];
        const float zv  = xz[(size_t)t * 1024 + 512 + c];
        const float dx  = dl * xcv;
        const bool f = sfirst[tt];
        float sum = 0.f;
        #pragma unroll
        for (int s = 0; s < NSTATE; s++) {
            const float a = f ? 0.f : __expf(dl * Areg[s]);
            h[s] = a * h[s] + dx * sBC[tt][s];
            sum += h[s] * sBC[tt][16 + s];
        }
        const float yv = sum + Dc * xcv;
        const float zs = zv / (1.f + __expf(-zv));
        yb[(size_t)t * E_DIM + c] = f2bf(yv * zs);
    }
}

extern "C" void kernel_launch(void* const* d_in, const int* in_sizes, int n_in,
                              void* d_out, int out_size, void* d_ws, size_t ws_size,
                              hipStream_t stream) {
    const float* q          = (const float*)d_in[0];
    const float* kv         = (const float*)d_in[1];
    const float* ke         = (const float*)d_in[2];
    const int*   index      = (const int*)d_in[3];
    const int*   eb         = (const int*)d_in[5];
    const float* w_weight   = (const float*)d_in[6];
    const float* w_bias     = (const float*)d_in[7];
    const float* in_proj_w  = (const float*)d_in[8];
    const float* conv_w     = (const float*)d_in[9];
    const float* conv_b     = (const float*)d_in[10];
    const float* x_proj_w   = (const float*)d_in[11];
    const float* dt_proj_w  = (const float*)d_in[12];
    const float* dt_proj_b  = (const float*)d_in[13];
    const float* A_log      = (const float*)d_in[14];
    const float* Dp         = (const float*)d_in[15];
    const float* out_proj_w = (const float*)d_in[16];
    float* out = (float*)d_out;

    // workspace layout (floats): total ~87.5 MB
    float* ws     = (float*)d_ws;
    float* xz     = ws;                                   // L*1024 = 32 MB
    float* xc     = xz + (size_t)L_SEQ * 1024;            // 16 MB
    float* dbc    = xc + (size_t)L_SEQ * 512;             // 2 MB
    float* delta  = dbc + (size_t)L_SEQ * 64;             // 16 MB
    float* h_init = delta + (size_t)L_SEQ * 512;          // NCHUNK*8192 = 4 MB
    float* statsR = h_init + (size_t)NCHUNK * 8192;       // 8 MB (stats, then y bf16)
    float* stats_a = statsR;
    float* stats_h = statsR + (size_t)NCHUNK * 8192;
    u16*  ybf = (u16*)statsR;                             // alias: stats dead after combine
    u16*  xbf = (u16*)(statsR + (size_t)2 * NCHUNK * 8192); // L*512 bf16 = 8 MB
    u16*  ipb = xbf + (size_t)L_SEQ * 512;                // 1 MB
    u16*  opb = ipb + (size_t)1024 * 512;                 // 0.5 MB

    hipMemsetAsync(d_out, 0, (size_t)out_size * sizeof(float), stream);

    // weight casts
    cast_bf16_kernel<<<dim3((1024 * 512 / 4 + 255) / 256), dim3(256), 0, stream>>>(
        in_proj_w, ipb, 1024 * 512 / 4);
    cast_bf16_kernel<<<dim3((512 * 512 / 4 + 255) / 256), dim3(256), 0, stream>>>(
        out_proj_w, opb, 512 * 512 / 4);

    // 1) xbf = leaky(cat(q,kv,ke) @ w_weight^T + w_bias)   [bf16 out]
    gemm1_mfma_kernel<<<dim3(E_DIM / 128, L_SEQ / 128), dim3(256), 0, stream>>>(
        q, kv, ke, w_weight, w_bias, xbf);
    // 2) xz = xbf @ in_proj^T  (f32 out, L x 1024)
    gemm_bf16_mfma_kernel<0><<<dim3(1024 / 128, L_SEQ / 128), dim3(256), 0, stream>>>(
        xbf, 512, ipb, 512, xz, 1024, 512, nullptr);
    // 3) xc = silu(segconv(xz[:, :512]))
    conv_kernel<<<dim3(E_DIM / 256, L_SEQ), dim3(256), 0, stream>>>(xz, conv_w, conv_b, eb, xc);
    // 4) dbc = xc @ x_proj^T  (L x 64)
    gemm_bt_kernel<0><<<dim3(1, L_SEQ / TILE), dim3(256), 0, stream>>>(
        xc, E_DIM, x_proj_w, E_DIM, dbc, 64, E_DIM, nullptr);
    // 5) delta = softplus(dbc[:, :32] @ dt_proj^T + dt_proj_b)
    gemm_bt_kernel<2><<<dim3(E_DIM / TILE, L_SEQ / TILE), dim3(256), 0, stream>>>(
        dbc, 64, dt_proj_w, 32, delta, E_DIM, 32, dt_proj_b);
    // 6) chunked parallel scan -> ybf (bf16)
    scan_chunk_local<<<dim3(NCHUNK), dim3(512), 0, stream>>>(
        delta, xc, dbc, A_log, eb, stats_a, stats_h);
    scan_chunk_combine<<<dim3(8192 / 256), dim3(256), 0, stream>>>(
        stats_a, stats_h, h_init);
    scan_chunk_final<<<dim3(NCHUNK), dim3(512), 0, stream>>>(
        delta, xc, xz, dbc, A_log, Dp, eb, h_init, ybf);
    // 7) out += segment_sum(ybf @ out_proj^T)
    gemm_bf16_mfma_kernel<1><<<dim3(E_DIM / 128, L_SEQ / 128), dim3(256), 0, stream>>>(
        ybf, 512, opb, 512, out, E_DIM, 512, index);
}

// Round 4
// 406.285 us; speedup vs baseline: 3.3744x; 1.0733x over previous
//
#include <hip/hip_runtime.h>
#include <hip/hip_bf16.h>
#include <math.h>

#define L_SEQ   8192
#define E_DIM   512
#define NSTATE  16
#define NGRAPH  16

#define TILE 64
#define KT   16

#define QCHUNK 32
#define NCHUNK (L_SEQ / QCHUNK)   // 256

typedef unsigned short u16;
typedef __attribute__((ext_vector_type(8))) short short8;
typedef __attribute__((ext_vector_type(4))) float floatx4;

__device__ __forceinline__ u16 f2bf(float f) {
    union { float f; unsigned u; } in; in.f = f;
    unsigned u = in.u;
    u += 0x7FFFu + ((u >> 16) & 1u);   // RNE
    return (u16)(u >> 16);
}

__device__ __forceinline__ void gl2lds16(const void* g, void* l) {
    __builtin_amdgcn_global_load_lds(
        (const __attribute__((address_space(1))) void*)g,
        (__attribute__((address_space(3))) void*)l, 16, 0, 0);
}

// convert 8 consecutive f32 -> 8 bf16, write 16B to LDS
__device__ __forceinline__ void stage_cvt8(const float* __restrict__ g, u16* lds) {
    const float4 a = *(const float4*)g;
    const float4 b = *(const float4*)(g + 4);
    union { short8 v; u16 u[8]; } t;
    t.u[0] = f2bf(a.x); t.u[1] = f2bf(a.y); t.u[2] = f2bf(a.z); t.u[3] = f2bf(a.w);
    t.u[4] = f2bf(b.x); t.u[5] = f2bf(b.y); t.u[6] = f2bf(b.z); t.u[7] = f2bf(b.w);
    *(short8*)lds = t.v;
}

// ---------------- MFMA GEMM (bf16 inputs in HBM), 128x128 tile ----------------
// C[M,N] = A[M,K] * B[N,K]^T. A,B bf16; C f32.
// EPI 0: plain f32 store. EPI 1: atomicAdd into C[index[m]][n] (segment sum).
template<int EPI>
__global__ __launch_bounds__(256) void gemm_bf16_mfma_kernel(
    const u16* __restrict__ A, int lda,
    const u16* __restrict__ B, int ldb,
    float* __restrict__ C, int ldc, int K,
    const int* __restrict__ index)
{
    __shared__ __align__(16) u16 As[128 * 32];
    __shared__ __align__(16) u16 Bs[128 * 32];
    const int tid  = threadIdx.x;
    const int lane = tid & 63;
    const int wave = tid >> 6;
    const int m0 = blockIdx.y * 128, n0 = blockIdx.x * 128;
    const int wm = (wave >> 1) * 64, wn = (wave & 1) * 64;
    const int ar0 = tid >> 2;            // chunk row (0..63)
    const int ak  = (tid & 3) * 8;       // chunk k offset

    const u16* pa0 = A + (size_t)(m0 + ar0) * lda + ak;
    const u16* pa1 = pa0 + (size_t)64 * lda;
    const u16* pb0 = B + (size_t)(n0 + ar0) * ldb + ak;
    const u16* pb1 = pb0 + (size_t)64 * ldb;
    u16* la0 = As + wave * 512;          // HW adds lane*16B
    u16* la1 = As + 2048 + wave * 512;
    u16* lb0 = Bs + wave * 512;
    u16* lb1 = Bs + 2048 + wave * 512;

    floatx4 acc[4][4] = {};
    const int r16 = lane & 15, kh = lane >> 4;

    for (int k0 = 0; k0 < K; k0 += 32) {
        gl2lds16(pa0 + k0, la0);
        gl2lds16(pa1 + k0, la1);
        gl2lds16(pb0 + k0, lb0);
        gl2lds16(pb1 + k0, lb1);
        __syncthreads();
        short8 af[4], bfr[4];
        #pragma unroll
        for (int i = 0; i < 4; i++) {
            af[i]  = *(const short8*)(As + (wm + i * 16 + r16) * 32 + kh * 8);
            bfr[i] = *(const short8*)(Bs + (wn + i * 16 + r16) * 32 + kh * 8);
        }
        #pragma unroll
        for (int i = 0; i < 4; i++)
            #pragma unroll
            for (int j = 0; j < 4; j++)
                acc[i][j] = __builtin_amdgcn_mfma_f32_16x16x32_bf16(af[i], bfr[j], acc[i][j], 0, 0, 0);
        __syncthreads();
    }

    #pragma unroll
    for (int i = 0; i < 4; i++) {
        #pragma unroll
        for (int r = 0; r < 4; r++) {
            const int m = m0 + wm + i * 16 + kh * 4 + r;
            #pragma unroll
            for (int j = 0; j < 4; j++) {
                const int n = n0 + wn + j * 16 + r16;
                const float v = acc[i][j][r];
                if (EPI == 0) {
                    C[(size_t)m * ldc + n] = v;
                } else {
                    atomicAdd(&C[(size_t)index[m] * ldc + n], v);
                }
            }
        }
    }
}

// GEMM1: Xb[L,512](bf16) = leaky(cat(q,kv,ke)[L,1536] @ W[512,1536]^T + bias)
__global__ __launch_bounds__(256) void gemm1_mfma_kernel(
    const float* __restrict__ q, const float* __restrict__ kv, const float* __restrict__ ke,
    const float* __restrict__ W,
    const float* __restrict__ bias,
    u16* __restrict__ Xb)
{
    __shared__ __align__(16) u16 As[128 * 32];
    __shared__ __align__(16) u16 Bs[128 * 32];
    const int tid  = threadIdx.x;
    const int lane = tid & 63;
    const int wave = tid >> 6;
    const int m0 = blockIdx.y * 128, n0 = blockIdx.x * 128;
    const int wm = (wave >> 1) * 64, wn = (wave & 1) * 64;
    const int ar0 = tid >> 2;
    const int ar1 = ar0 + 64;
    const int ak  = (tid & 3) * 8;

    floatx4 acc[4][4] = {};
    const int r16 = lane & 15, kh = lane >> 4;

    for (int k0 = 0; k0 < 3 * E_DIM; k0 += 32) {
        const int kg = k0 + ak;
        const float* asrc = (kg < 512) ? q : ((kg < 1024) ? kv : ke);
        const int acol = kg & 511;
        stage_cvt8(asrc + (size_t)(m0 + ar0) * 512 + acol, As + tid * 8);
        stage_cvt8(asrc + (size_t)(m0 + ar1) * 512 + acol, As + 2048 + tid * 8);
        stage_cvt8(W + (size_t)(n0 + ar0) * 1536 + kg, Bs + tid * 8);
        stage_cvt8(W + (size_t)(n0 + ar1) * 1536 + kg, Bs + 2048 + tid * 8);
        __syncthreads();
        short8 af[4], bfr[4];
        #pragma unroll
        for (int i = 0; i < 4; i++) {
            af[i]  = *(const short8*)(As + (wm + i * 16 + r16) * 32 + kh * 8);
            bfr[i] = *(const short8*)(Bs + (wn + i * 16 + r16) * 32 + kh * 8);
        }
        #pragma unroll
        for (int i = 0; i < 4; i++)
            #pragma unroll
            for (int j = 0; j < 4; j++)
                acc[i][j] = __builtin_amdgcn_mfma_f32_16x16x32_bf16(af[i], bfr[j], acc[i][j], 0, 0, 0);
        __syncthreads();
    }

    #pragma unroll
    for (int i = 0; i < 4; i++) {
        #pragma unroll
        for (int r = 0; r < 4; r++) {
            const int m = m0 + wm + i * 16 + kh * 4 + r;
            #pragma unroll
            for (int j = 0; j < 4; j++) {
                const int n = n0 + wn + j * 16 + r16;
                float v = acc[i][j][r] + bias[n];
                v = (v >= 0.f) ? v : 0.01f * v;
                Xb[(size_t)m * 512 + n] = f2bf(v);
            }
        }
    }
}

// f32 -> bf16 bulk cast (n4 = n/4)
__global__ __launch_bounds__(256) void cast_bf16_kernel(
    const float* __restrict__ s, u16* __restrict__ d, int n4)
{
    const int i = blockIdx.x * 256 + threadIdx.x;
    if (i >= n4) return;
    const float4 v = ((const float4*)s)[i];
    ushort4 u;
    u.x = f2bf(v.x); u.y = f2bf(v.y); u.z = f2bf(v.z); u.w = f2bf(v.w);
    ((ushort4*)d)[i] = u;
}

// ---------------- f32 tile GEMM for the two small GEMMs ----------------
// EPI: 0 = store, 2 = +bias,softplus
template<int EPI>
__global__ __launch_bounds__(256) void gemm_bt_kernel(
    const float* __restrict__ A, int lda,
    const float* __restrict__ B, int ldb,
    float* __restrict__ C, int ldc,
    int K,
    const float* __restrict__ bias)
{
    __shared__ float As[TILE][KT + 1];
    __shared__ float Bs[TILE][KT + 1];
    const int tid = threadIdx.x;
    const int ty = tid >> 4, tx = tid & 15;
    const int m0 = blockIdx.y * TILE, n0 = blockIdx.x * TILE;
    const int lrow = tid >> 2;
    const int lk = (tid & 3) << 2;
    float acc[4][4] = {};

    for (int k0 = 0; k0 < K; k0 += KT) {
        float4 av = *(const float4*)(A + (size_t)(m0 + lrow) * lda + k0 + lk);
        float4 bv = *(const float4*)(B + (size_t)(n0 + lrow) * ldb + k0 + lk);
        As[lrow][lk + 0] = av.x; As[lrow][lk + 1] = av.y;
        As[lrow][lk + 2] = av.z; As[lrow][lk + 3] = av.w;
        Bs[lrow][lk + 0] = bv.x; Bs[lrow][lk + 1] = bv.y;
        Bs[lrow][lk + 2] = bv.z; Bs[lrow][lk + 3] = bv.w;
        __syncthreads();
        #pragma unroll
        for (int kk = 0; kk < KT; kk++) {
            float a[4], b[4];
            #pragma unroll
            for (int i = 0; i < 4; i++) a[i] = As[ty * 4 + i][kk];
            #pragma unroll
            for (int j = 0; j < 4; j++) b[j] = Bs[tx * 4 + j][kk];
            #pragma unroll
            for (int i = 0; i < 4; i++)
                #pragma unroll
                for (int j = 0; j < 4; j++)
                    acc[i][j] += a[i] * b[j];
        }
        __syncthreads();
    }

    #pragma unroll
    for (int i = 0; i < 4; i++) {
        const int m = m0 + ty * 4 + i;
        #pragma unroll
        for (int j = 0; j < 4; j++) {
            const int n = n0 + tx * 4 + j;
            float v = acc[i][j];
            if (EPI == 0) {
                C[(size_t)m * ldc + n] = v;
            } else {
                v += bias[n];
                float sp = (v > 0.f) ? (v + log1pf(__expf(-v))) : log1pf(__expf(v));
                C[(size_t)m * ldc + n] = sp;
            }
        }
    }
}

// xc[t,c] = silu(conv_b[c] + sum_k conv_w[c,k]*x_in[t+k-3,c]*(seg match))
__global__ __launch_bounds__(256) void conv_kernel(
    const float* __restrict__ xz,
    const float* __restrict__ conv_w,
    const float* __restrict__ conv_b,
    const int* __restrict__ eb,
    float* __restrict__ xc)
{
    const int t = blockIdx.y;
    const int c = blockIdx.x * blockDim.x + threadIdx.x;
    const int ebt = eb[t];
    float acc = conv_b[c];
    #pragma unroll
    for (int k = 0; k < 4; k++) {
        const int j = t + k - 3;
        if (j >= 0 && eb[j] == ebt)
            acc += conv_w[c * 4 + k] * xz[(size_t)j * 1024 + c];
    }
    xc[(size_t)t * E_DIM + c] = acc / (1.f + __expf(-acc));
}

// ---------------- Chunked parallel selective scan ----------------
// grid (NCHUNK, 2), 256 threads: block handles chunk k, channels [half*256, half*256+256)

__global__ __launch_bounds__(256) void scan_chunk_local(
    const float* __restrict__ delta,
    const float* __restrict__ xc,
    const float* __restrict__ dbc,
    const float* __restrict__ A_log,
    const int* __restrict__ eb,
    float* __restrict__ stats_a,
    float* __restrict__ stats_h)
{
    const int k = blockIdx.x;
    const int c = blockIdx.y * 256 + threadIdx.x;
    const int t0 = k * QCHUNK;

    __shared__ float sBC[QCHUNK][32];
    __shared__ int sfirst[QCHUNK];
    for (int i = threadIdx.x; i < QCHUNK * 32; i += 256)
        sBC[i >> 5][i & 31] = dbc[(size_t)(t0 + (i >> 5)) * 64 + 32 + (i & 31)];
    if (threadIdx.x < QCHUNK) {
        const int t = t0 + threadIdx.x;
        sfirst[threadIdx.x] = (t == 0) || (eb[t] != eb[t - 1]);
    }
    __syncthreads();

    float Areg[NSTATE];
    #pragma unroll
    for (int s = 0; s < NSTATE; s++) Areg[s] = -__expf(A_log[c * NSTATE + s]);
    float h[NSTATE], ap[NSTATE];
    #pragma unroll
    for (int s = 0; s < NSTATE; s++) { h[s] = 0.f; ap[s] = 1.f; }

    for (int tt = 0; tt < QCHUNK; tt++) {
        const int t = t0 + tt;
        const float dl = delta[(size_t)t * E_DIM + c];
        const float dx = dl * xc[(size_t)t * E_DIM + c];
        const bool f = sfirst[tt];
        #pragma unroll
        for (int s = 0; s < NSTATE; s++) {
            const float a = f ? 0.f : __expf(dl * Areg[s]);
            ap[s] *= a;
            h[s] = a * h[s] + dx * sBC[tt][s];
        }
    }
    #pragma unroll
    for (int s = 0; s < NSTATE; s++) {
        const size_t o = ((size_t)k * NSTATE + s) * E_DIM + c;
        stats_a[o] = ap[s];
        stats_h[o] = h[s];
    }
}

// Combine: sequential over chunks; writes h_init IN PLACE over stats_a.
__global__ __launch_bounds__(256) void scan_chunk_combine(
    float* __restrict__ stats_a,          // in: a-products, out: h_init
    const float* __restrict__ stats_h)
{
    const int tid = blockIdx.x * 256 + threadIdx.x;   // 0..8191 = s*512+c
    float h = 0.f;
    #pragma unroll 4
    for (int k = 0; k < NCHUNK; k++) {
        const size_t o = (size_t)k * (E_DIM * NSTATE) + tid;
        const float a  = stats_a[o];
        const float hs = stats_h[o];
        stats_a[o] = h;            // h entering chunk k
        h = a * h + hs;
    }
}

__global__ __launch_bounds__(256) void scan_chunk_final(
    const float* __restrict__ delta,
    const float* __restrict__ xc,
    const float* __restrict__ xz,
    const float* __restrict__ dbc,
    const float* __restrict__ A_log,
    const float* __restrict__ Dp,
    const int* __restrict__ eb,
    const float* __restrict__ h_init,
    u16* __restrict__ yb)
{
    const int k = blockIdx.x;
    const int c = blockIdx.y * 256 + threadIdx.x;
    const int t0 = k * QCHUNK;

    __shared__ float sBC[QCHUNK][32];
    __shared__ int sfirst[QCHUNK];
    for (int i = threadIdx.x; i < QCHUNK * 32; i += 256)
        sBC[i >> 5][i & 31] = dbc[(size_t)(t0 + (i >> 5)) * 64 + 32 + (i & 31)];
    if (threadIdx.x < QCHUNK) {
        const int t = t0 + threadIdx.x;
        sfirst[threadIdx.x] = (t == 0) || (eb[t] != eb[t - 1]);
    }
    __syncthreads();

    float Areg[NSTATE];
    #pragma unroll
    for (int s = 0; s < NSTATE; s++) Areg[s] = -__expf(A_log[c * NSTATE + s]);
    const float Dc = Dp[c];
    float h[NSTATE];
    #pragma unroll
    for (int s = 0; s < NSTATE; s++)
        h[s] = h_init[(size_t)k * (E_DIM * NSTATE) + s * E_DIM + c];

    for (int tt = 0; tt < QCHUNK; tt++) {
        const int t = t0 + tt;
        const float dl  = delta[(size_t)t * E_DIM + c];
        const float xcv = xc[(size_t)t * E_DIM + c];
        const float zv  = xz[(size_t)t * 1024 + 512 + c];
        const float dx  = dl * xcv;
        const bool f = sfirst[tt];
        float sum = 0.f;
        #pragma unroll
        for (int s = 0; s < NSTATE; s++) {
            const float a = f ? 0.f : __expf(dl * Areg[s]);
            h[s] = a * h[s] + dx * sBC[tt][s];
            sum += h[s] * sBC[tt][16 + s];
        }
        const float yv = sum + Dc * xcv;
        const float zs = zv / (1.f + __expf(-zv));
        yb[(size_t)t * E_DIM + c] = f2bf(yv * zs);
    }
}

extern "C" void kernel_launch(void* const* d_in, const int* in_sizes, int n_in,
                              void* d_out, int out_size, void* d_ws, size_t ws_size,
                              hipStream_t stream) {
    const float* q          = (const float*)d_in[0];
    const float* kv         = (const float*)d_in[1];
    const float* ke         = (const float*)d_in[2];
    const int*   index      = (const int*)d_in[3];
    const int*   eb         = (const int*)d_in[5];
    const float* w_weight   = (const float*)d_in[6];
    const float* w_bias     = (const float*)d_in[7];
    const float* in_proj_w  = (const float*)d_in[8];
    const float* conv_w     = (const float*)d_in[9];
    const float* conv_b     = (const float*)d_in[10];
    const float* x_proj_w   = (const float*)d_in[11];
    const float* dt_proj_w  = (const float*)d_in[12];
    const float* dt_proj_b  = (const float*)d_in[13];
    const float* A_log      = (const float*)d_in[14];
    const float* Dp         = (const float*)d_in[15];
    const float* out_proj_w = (const float*)d_in[16];
    float* out = (float*)d_out;

    // workspace layout (floats). Peak ~83.5 MB.
    float* ws     = (float*)d_ws;
    float* xz     = ws;                                   // L*1024 = 32 MB
    float* xc     = xz + (size_t)L_SEQ * 1024;            // 16 MB
    float* dbc    = xc + (size_t)L_SEQ * 512;             // 2 MB
    float* delta  = dbc + (size_t)L_SEQ * 64;             // 16 MB
    float* S1     = delta + (size_t)L_SEQ * 512;          // NCHUNK*8192 = 8 MB
    float* S2     = S1 + (size_t)NCHUNK * 8192;           // 8 MB
    u16*   ipb    = (u16*)(S2 + (size_t)NCHUNK * 8192);   // 1 MB
    u16*   opb    = ipb + (size_t)1024 * 512;             // 0.5 MB

    // aliases:
    u16*   xbf     = (u16*)S1;   // bf16 x (live gemm1 -> gemm2, dead before pass1)
    float* stats_a = S1;         // pass1 -> combine; combine rewrites as h_init
    float* stats_h = S2;         // pass1 -> combine
    float* h_init  = S1;         // combine -> pass3
    u16*   ybf     = (u16*)S2;   // pass3 -> gemm7 (stats_h dead after combine)

    hipMemsetAsync(d_out, 0, (size_t)out_size * sizeof(float), stream);

    // weight casts
    cast_bf16_kernel<<<dim3((1024 * 512 / 4 + 255) / 256), dim3(256), 0, stream>>>(
        in_proj_w, ipb, 1024 * 512 / 4);
    cast_bf16_kernel<<<dim3((512 * 512 / 4 + 255) / 256), dim3(256), 0, stream>>>(
        out_proj_w, opb, 512 * 512 / 4);

    // 1) xbf = leaky(cat(q,kv,ke) @ w_weight^T + w_bias)   [bf16 out]
    gemm1_mfma_kernel<<<dim3(E_DIM / 128, L_SEQ / 128), dim3(256), 0, stream>>>(
        q, kv, ke, w_weight, w_bias, xbf);
    // 2) xz = xbf @ in_proj^T  (f32 out, L x 1024)
    gemm_bf16_mfma_kernel<0><<<dim3(1024 / 128, L_SEQ / 128), dim3(256), 0, stream>>>(
        xbf, 512, ipb, 512, xz, 1024, 512, nullptr);
    // 3) xc = silu(segconv(xz[:, :512]))
    conv_kernel<<<dim3(E_DIM / 256, L_SEQ), dim3(256), 0, stream>>>(xz, conv_w, conv_b, eb, xc);
    // 4) dbc = xc @ x_proj^T  (L x 64)
    gemm_bt_kernel<0><<<dim3(1, L_SEQ / TILE), dim3(256), 0, stream>>>(
        xc, E_DIM, x_proj_w, E_DIM, dbc, 64, E_DIM, nullptr);
    // 5) delta = softplus(dbc[:, :32] @ dt_proj^T + dt_proj_b)
    gemm_bt_kernel<2><<<dim3(E_DIM / TILE, L_SEQ / TILE), dim3(256), 0, stream>>>(
        dbc, 64, dt_proj_w, 32, delta, E_DIM, 32, dt_proj_b);
    // 6) chunked parallel scan -> ybf (bf16)
    scan_chunk_local<<<dim3(NCHUNK, 2), dim3(256), 0, stream>>>(
        delta, xc, dbc, A_log, eb, stats_a, stats_h);
    scan_chunk_combine<<<dim3(8192 / 256), dim3(256), 0, stream>>>(
        stats_a, stats_h);
    scan_chunk_final<<<dim3(NCHUNK, 2), dim3(256), 0, stream>>>(
        delta, xc, xz, dbc, A_log, Dp, eb, h_init, ybf);
    // 7) out += segment_sum(ybf @ out_proj^T)
    gemm_bf16_mfma_kernel<1><<<dim3(E_DIM / 128, L_SEQ / 128), dim3(256), 0, stream>>>(
        ybf, 512, opb, 512, out, E_DIM, 512, index);
}

// Round 5
// 363.799 us; speedup vs baseline: 3.7685x; 1.1168x over previous
//
#include <hip/hip_runtime.h>
#include <hip/hip_bf16.h>
#include <math.h>

#define L_SEQ   8192
#define E_DIM   512
#define NSTATE  16

#define TILE 64
#define KT   16

#define QCHUNK 32
#define NCHUNK (L_SEQ / QCHUNK)   // 256

typedef unsigned short u16;
typedef __attribute__((ext_vector_type(8))) short short8;
typedef __attribute__((ext_vector_type(4))) float floatx4;

__device__ __forceinline__ u16 f2bf(float f) {
    union { float f; unsigned u; } in; in.f = f;
    unsigned u = in.u;
    u += 0x7FFFu + ((u >> 16) & 1u);   // RNE
    return (u16)(u >> 16);
}

__device__ __forceinline__ void gl2lds16(const void* g, void* l) {
    __builtin_amdgcn_global_load_lds(
        (const __attribute__((address_space(1))) void*)g,
        (__attribute__((address_space(3))) void*)l, 16, 0, 0);
}

// ---------------- MFMA GEMM, tile M=128 x N=64, 4 waves (wave = 32 rows x 64 cols) ----------------
// C[M,N] = A[M,K] * B[N,K]^T. A,B bf16 in HBM (global_load_lds staging).
// EPI 0: f32 store. EPI 1: atomic segment-sum via index[m]. EPI 2: +bias, leaky, bf16 store.
template<int EPI>
__global__ __launch_bounds__(256) void gemm_bf16_64(
    const u16* __restrict__ A, int lda,
    const u16* __restrict__ B, int ldb,
    void* __restrict__ Cout, int ldc, int K,
    const float* __restrict__ bias,
    const int* __restrict__ index)
{
    __shared__ __align__(16) u16 As[128 * 32];
    __shared__ __align__(16) u16 Bs[64 * 32];
    const int tid  = threadIdx.x;
    const int lane = tid & 63;
    const int wave = tid >> 6;
    const int m0 = blockIdx.y * 128, n0 = blockIdx.x * 64;
    const int row = tid >> 2;            // 0..63
    const int kk8 = (tid & 3) * 8;

    const u16* pa0 = A + (size_t)(m0 + row) * lda + kk8;
    const u16* pa1 = pa0 + (size_t)64 * lda;
    const u16* pb  = B + (size_t)(n0 + row) * ldb + kk8;
    u16* la0 = As + wave * 512;
    u16* la1 = As + 2048 + wave * 512;
    u16* lb  = Bs + wave * 512;

    floatx4 acc[2][4] = {};
    const int r16 = lane & 15, kh = lane >> 4;

    for (int k0 = 0; k0 < K; k0 += 32) {
        gl2lds16(pa0 + k0, la0);
        gl2lds16(pa1 + k0, la1);
        gl2lds16(pb + k0, lb);
        __syncthreads();
        short8 af[2], bfr[4];
        #pragma unroll
        for (int i = 0; i < 2; i++)
            af[i] = *(const short8*)(As + (wave * 32 + i * 16 + r16) * 32 + kh * 8);
        #pragma unroll
        for (int j = 0; j < 4; j++)
            bfr[j] = *(const short8*)(Bs + (j * 16 + r16) * 32 + kh * 8);
        #pragma unroll
        for (int i = 0; i < 2; i++)
            #pragma unroll
            for (int j = 0; j < 4; j++)
                acc[i][j] = __builtin_amdgcn_mfma_f32_16x16x32_bf16(af[i], bfr[j], acc[i][j], 0, 0, 0);
        __syncthreads();
    }

    #pragma unroll
    for (int i = 0; i < 2; i++) {
        #pragma unroll
        for (int r = 0; r < 4; r++) {
            const int m = m0 + wave * 32 + i * 16 + kh * 4 + r;
            #pragma unroll
            for (int j = 0; j < 4; j++) {
                const int n = n0 + j * 16 + r16;
                float v = acc[i][j][r];
                if (EPI == 0) {
                    ((float*)Cout)[(size_t)m * ldc + n] = v;
                } else if (EPI == 1) {
                    atomicAdd(&((float*)Cout)[(size_t)index[m] * ldc + n], v);
                } else {
                    v += bias[n];
                    v = (v >= 0.f) ? v : 0.01f * v;
                    ((u16*)Cout)[(size_t)m * ldc + n] = f2bf(v);
                }
            }
        }
    }
}

// f32 -> bf16 bulk cast (n4 = n/4)
__global__ __launch_bounds__(256) void cast_bf16_kernel(
    const float* __restrict__ s, u16* __restrict__ d, int n4)
{
    const int i = blockIdx.x * 256 + threadIdx.x;
    if (i >= n4) return;
    const float4 v = ((const float4*)s)[i];
    ushort4 u;
    u.x = f2bf(v.x); u.y = f2bf(v.y); u.z = f2bf(v.z); u.w = f2bf(v.w);
    ((ushort4*)d)[i] = u;
}

// cast q/kv/ke (f32, [L,512] each) into concatenated bf16 catA [L,1536]
__global__ __launch_bounds__(256) void cast_cat_kernel(
    const float* __restrict__ q, const float* __restrict__ kv, const float* __restrict__ ke,
    u16* __restrict__ catA)
{
    const int src = blockIdx.y;
    const float* s = (src == 0) ? q : ((src == 1) ? kv : ke);
    const int i = blockIdx.x * 256 + threadIdx.x;    // one float4 per thread
    const int t = i >> 7;                            // row
    const int c = (i & 127) << 2;
    const float4 v = ((const float4*)s)[i];
    ushort4 u;
    u.x = f2bf(v.x); u.y = f2bf(v.y); u.z = f2bf(v.z); u.w = f2bf(v.w);
    *(ushort4*)(catA + (size_t)t * 1536 + src * 512 + c) = u;
}

// ---------------- f32 tile GEMM (only for dt_proj, K=32) ----------------
template<int EPI>
__global__ __launch_bounds__(256) void gemm_bt_kernel(
    const float* __restrict__ A, int lda,
    const float* __restrict__ B, int ldb,
    float* __restrict__ C, int ldc,
    int K,
    const float* __restrict__ bias)
{
    __shared__ float As[TILE][KT + 1];
    __shared__ float Bs[TILE][KT + 1];
    const int tid = threadIdx.x;
    const int ty = tid >> 4, tx = tid & 15;
    const int m0 = blockIdx.y * TILE, n0 = blockIdx.x * TILE;
    const int lrow = tid >> 2;
    const int lk = (tid & 3) << 2;
    float acc[4][4] = {};

    for (int k0 = 0; k0 < K; k0 += KT) {
        float4 av = *(const float4*)(A + (size_t)(m0 + lrow) * lda + k0 + lk);
        float4 bv = *(const float4*)(B + (size_t)(n0 + lrow) * ldb + k0 + lk);
        As[lrow][lk + 0] = av.x; As[lrow][lk + 1] = av.y;
        As[lrow][lk + 2] = av.z; As[lrow][lk + 3] = av.w;
        Bs[lrow][lk + 0] = bv.x; Bs[lrow][lk + 1] = bv.y;
        Bs[lrow][lk + 2] = bv.z; Bs[lrow][lk + 3] = bv.w;
        __syncthreads();
        #pragma unroll
        for (int kk = 0; kk < KT; kk++) {
            float a[4], b[4];
            #pragma unroll
            for (int i = 0; i < 4; i++) a[i] = As[ty * 4 + i][kk];
            #pragma unroll
            for (int j = 0; j < 4; j++) b[j] = Bs[tx * 4 + j][kk];
            #pragma unroll
            for (int i = 0; i < 4; i++)
                #pragma unroll
                for (int j = 0; j < 4; j++)
                    acc[i][j] += a[i] * b[j];
        }
        __syncthreads();
    }

    #pragma unroll
    for (int i = 0; i < 4; i++) {
        const int m = m0 + ty * 4 + i;
        #pragma unroll
        for (int j = 0; j < 4; j++) {
            const int n = n0 + tx * 4 + j;
            float v = acc[i][j];
            if (EPI == 0) {
                C[(size_t)m * ldc + n] = v;
            } else {
                v += bias[n];
                float sp = (v > 0.f) ? (v + log1pf(__expf(-v))) : log1pf(__expf(v));
                C[(size_t)m * ldc + n] = sp;
            }
        }
    }
}

// xc = silu(segconv(xz[:, :512])); emits f32 (scan) and bf16 (x_proj MFMA)
__global__ __launch_bounds__(256) void conv_kernel(
    const float* __restrict__ xz,
    const float* __restrict__ conv_w,
    const float* __restrict__ conv_b,
    const int* __restrict__ eb,
    float* __restrict__ xc,
    u16* __restrict__ xcb)
{
    const int t = blockIdx.y;
    const int c = blockIdx.x * blockDim.x + threadIdx.x;
    const int ebt = eb[t];
    float acc = conv_b[c];
    #pragma unroll
    for (int k = 0; k < 4; k++) {
        const int j = t + k - 3;
        if (j >= 0 && eb[j] == ebt)
            acc += conv_w[c * 4 + k] * xz[(size_t)j * 1024 + c];
    }
    const float v = acc / (1.f + __expf(-acc));
    xc[(size_t)t * E_DIM + c] = v;
    xcb[(size_t)t * E_DIM + c] = f2bf(v);
}

// ---------------- Chunked parallel selective scan ----------------
// grid (NCHUNK, 2), 256 threads

__global__ __launch_bounds__(256) void scan_chunk_local(
    const float* __restrict__ delta,
    const float* __restrict__ xc,
    const float* __restrict__ dbc,
    const float* __restrict__ A_log,
    const int* __restrict__ eb,
    float* __restrict__ stats_a,
    float* __restrict__ stats_h)
{
    const int k = blockIdx.x;
    const int c = blockIdx.y * 256 + threadIdx.x;
    const int t0 = k * QCHUNK;

    __shared__ float sBC[QCHUNK][32];
    __shared__ int sfirst[QCHUNK];
    for (int i = threadIdx.x; i < QCHUNK * 32; i += 256)
        sBC[i >> 5][i & 31] = dbc[(size_t)(t0 + (i >> 5)) * 64 + 32 + (i & 31)];
    if (threadIdx.x < QCHUNK) {
        const int t = t0 + threadIdx.x;
        sfirst[threadIdx.x] = (t == 0) || (eb[t] != eb[t - 1]);
    }
    __syncthreads();

    float Areg[NSTATE];
    #pragma unroll
    for (int s = 0; s < NSTATE; s++) Areg[s] = -__expf(A_log[c * NSTATE + s]);
    float h[NSTATE], ap[NSTATE];
    #pragma unroll
    for (int s = 0; s < NSTATE; s++) { h[s] = 0.f; ap[s] = 1.f; }

    for (int tt = 0; tt < QCHUNK; tt++) {
        const int t = t0 + tt;
        const float dl = delta[(size_t)t * E_DIM + c];
        const float dx = dl * xc[(size_t)t * E_DIM + c];
        const bool f = sfirst[tt];
        #pragma unroll
        for (int s = 0; s < NSTATE; s++) {
            const float a = f ? 0.f : __expf(dl * Areg[s]);
            ap[s] *= a;
            h[s] = a * h[s] + dx * sBC[tt][s];
        }
    }
    #pragma unroll
    for (int s = 0; s < NSTATE; s++) {
        const size_t o = ((size_t)k * NSTATE + s) * E_DIM + c;
        stats_a[o] = ap[s];
        stats_h[o] = h[s];
    }
}

__global__ __launch_bounds__(256) void scan_chunk_combine(
    float* __restrict__ stats_a,          // in: a-products, out: h_init (in place)
    const float* __restrict__ stats_h)
{
    const int tid = blockIdx.x * 256 + threadIdx.x;
    float h = 0.f;
    #pragma unroll 4
    for (int k = 0; k < NCHUNK; k++) {
        const size_t o = (size_t)k * (E_DIM * NSTATE) + tid;
        const float a  = stats_a[o];
        const float hs = stats_h[o];
        stats_a[o] = h;
        h = a * h + hs;
    }
}

__global__ __launch_bounds__(256) void scan_chunk_final(
    const float* __restrict__ delta,
    const float* __restrict__ xc,
    const float* __restrict__ xz,
    const float* __restrict__ dbc,
    const float* __restrict__ A_log,
    const float* __restrict__ Dp,
    const int* __restrict__ eb,
    const float* __restrict__ h_init,
    u16* __restrict__ yb)
{
    const int k = blockIdx.x;
    const int c = blockIdx.y * 256 + threadIdx.x;
    const int t0 = k * QCHUNK;

    __shared__ float sBC[QCHUNK][32];
    __shared__ int sfirst[QCHUNK];
    for (int i = threadIdx.x; i < QCHUNK * 32; i += 256)
        sBC[i >> 5][i & 31] = dbc[(size_t)(t0 + (i >> 5)) * 64 + 32 + (i & 31)];
    if (threadIdx.x < QCHUNK) {
        const int t = t0 + threadIdx.x;
        sfirst[threadIdx.x] = (t == 0) || (eb[t] != eb[t - 1]);
    }
    __syncthreads();

    float Areg[NSTATE];
    #pragma unroll
    for (int s = 0; s < NSTATE; s++) Areg[s] = -__expf(A_log[c * NSTATE + s]);
    const float Dc = Dp[c];
    float h[NSTATE];
    #pragma unroll
    for (int s = 0; s < NSTATE; s++)
        h[s] = h_init[(size_t)k * (E_DIM * NSTATE) + s * E_DIM + c];

    for (int tt = 0; tt < QCHUNK; tt++) {
        const int t = t0 + tt;
        const float dl  = delta[(size_t)t * E_DIM + c];
        const float xcv = xc[(size_t)t * E_DIM + c];
        const float zv  = xz[(size_t)t * 1024 + 512 + c];
        const float dx  = dl * xcv;
        const bool f = sfirst[tt];
        float sum = 0.f;
        #pragma unroll
        for (int s = 0; s < NSTATE; s++) {
            const float a = f ? 0.f : __expf(dl * Areg[s]);
            h[s] = a * h[s] + dx * sBC[tt][s];
            sum += h[s] * sBC[tt][16 + s];
        }
        const float yv = sum + Dc * xcv;
        const float zs = zv / (1.f + __expf(-zv));
        yb[(size_t)t * E_DIM + c] = f2bf(yv * zs);
    }
}

extern "C" void kernel_launch(void* const* d_in, const int* in_sizes, int n_in,
                              void* d_out, int out_size, void* d_ws, size_t ws_size,
                              hipStream_t stream) {
    const float* q          = (const float*)d_in[0];
    const float* kv         = (const float*)d_in[1];
    const float* ke         = (const float*)d_in[2];
    const int*   index      = (const int*)d_in[3];
    const int*   eb         = (const int*)d_in[5];
    const float* w_weight   = (const float*)d_in[6];
    const float* w_bias     = (const float*)d_in[7];
    const float* in_proj_w  = (const float*)d_in[8];
    const float* conv_w     = (const float*)d_in[9];
    const float* conv_b     = (const float*)d_in[10];
    const float* x_proj_w   = (const float*)d_in[11];
    const float* dt_proj_w  = (const float*)d_in[12];
    const float* dt_proj_b  = (const float*)d_in[13];
    const float* A_log      = (const float*)d_in[14];
    const float* Dp         = (const float*)d_in[15];
    const float* out_proj_w = (const float*)d_in[16];
    float* out = (float*)d_out;

    // workspace (floats). Real allocs total ~89.2 MB (ws proven >= 91.75 MB).
    float* ws     = (float*)d_ws;
    float* xz     = ws;                                   // 32 MB
    float* xc     = xz + (size_t)L_SEQ * 1024;            // 16 MB
    float* dbc    = xc + (size_t)L_SEQ * 512;             // 2 MB
    float* delta  = dbc + (size_t)L_SEQ * 64;             // 16 MB
    float* S1     = delta + (size_t)L_SEQ * 512;          // 8 MB
    float* S2     = S1 + (size_t)NCHUNK * 8192;           // 8 MB
    u16*   ipb    = (u16*)(S2 + (size_t)NCHUNK * 8192);   // 1 MB
    u16*   opb    = ipb + (size_t)1024 * 512;             // 0.5 MB
    u16*   wwb    = opb + (size_t)512 * 512;              // 1.5 MB
    u16*   xpb    = wwb + (size_t)512 * 1536;             // 64 KB

    // aliases (time-disjoint):
    u16*   catA    = (u16*)delta;  // 24 MB = delta+S1; dead after gemm1 (delta written at gemm5, S1 at scan)
    u16*   xbf     = (u16*)S2;     // gemm1 -> gemm2; dead before scan_local writes stats_h
    u16*   xcb     = (u16*)delta;  // conv -> gemm4; dead before gemm5 writes delta. (catA dead by conv)
    float* stats_a = S1;           // scan_local -> combine (in-place h_init) -> final
    float* stats_h = S2;
    float* h_init  = S1;
    u16*   ybf     = (u16*)S2;     // scan_final -> gemm7 (stats_h dead after combine)

    hipMemsetAsync(d_out, 0, (size_t)out_size * sizeof(float), stream);

    // casts
    cast_cat_kernel<<<dim3(L_SEQ * 512 / 4 / 256, 3), dim3(256), 0, stream>>>(q, kv, ke, catA);
    cast_bf16_kernel<<<dim3(512 * 1536 / 4 / 256), dim3(256), 0, stream>>>(w_weight, wwb, 512 * 1536 / 4);
    cast_bf16_kernel<<<dim3(1024 * 512 / 4 / 256), dim3(256), 0, stream>>>(in_proj_w, ipb, 1024 * 512 / 4);
    cast_bf16_kernel<<<dim3(512 * 512 / 4 / 256), dim3(256), 0, stream>>>(out_proj_w, opb, 512 * 512 / 4);
    cast_bf16_kernel<<<dim3(64 * 512 / 4 / 256), dim3(256), 0, stream>>>(x_proj_w, xpb, 64 * 512 / 4);

    // 1) xbf = leaky(catA @ wwb^T + w_bias)    [bf16 out], grid (512/64, 8192/128) = (8,64)
    gemm_bf16_64<2><<<dim3(8, 64), dim3(256), 0, stream>>>(
        catA, 1536, wwb, 1536, xbf, 512, 1536, w_bias, nullptr);
    // 2) xz = xbf @ ipb^T  (f32, L x 1024), grid (16,64)
    gemm_bf16_64<0><<<dim3(16, 64), dim3(256), 0, stream>>>(
        xbf, 512, ipb, 512, xz, 1024, 512, nullptr, nullptr);
    // 3) xc, xcb = silu(segconv(xz[:, :512]))
    conv_kernel<<<dim3(2, L_SEQ), dim3(256), 0, stream>>>(xz, conv_w, conv_b, eb, xc, xcb);
    // 4) dbc = xcb @ xpb^T  (f32, L x 64), grid (1,64)
    gemm_bf16_64<0><<<dim3(1, 64), dim3(256), 0, stream>>>(
        xcb, 512, xpb, 512, dbc, 64, 512, nullptr, nullptr);
    // 5) delta = softplus(dbc[:, :32] @ dt_proj^T + dt_proj_b)  (f32 VALU, K=32)
    gemm_bt_kernel<2><<<dim3(E_DIM / TILE, L_SEQ / TILE), dim3(256), 0, stream>>>(
        dbc, 64, dt_proj_w, 32, delta, E_DIM, 32, dt_proj_b);
    // 6) chunked parallel scan -> ybf (bf16)
    scan_chunk_local<<<dim3(NCHUNK, 2), dim3(256), 0, stream>>>(
        delta, xc, dbc, A_log, eb, stats_a, stats_h);
    scan_chunk_combine<<<dim3(8192 / 256), dim3(256), 0, stream>>>(stats_a, stats_h);
    scan_chunk_final<<<dim3(NCHUNK, 2), dim3(256), 0, stream>>>(
        delta, xc, xz, dbc, A_log, Dp, eb, h_init, ybf);
    // 7) out += segment_sum(ybf @ opb^T), grid (8,64)
    gemm_bf16_64<1><<<dim3(8, 64), dim3(256), 0, stream>>>(
        ybf, 512, opb, 512, out, 512, 512, nullptr, index);
}

// Round 6
// 344.628 us; speedup vs baseline: 3.9781x; 1.0556x over previous
//
#include <hip/hip_runtime.h>
#include <hip/hip_bf16.h>
#include <math.h>

#define L_SEQ   8192
#define E_DIM   512
#define NSTATE  16

#define QCHUNK  16
#define NCHUNK  (L_SEQ / QCHUNK)    // 512
#define GROUP   32                  // chunks per combine group
#define NGROUP  (NCHUNK / GROUP)    // 16

typedef unsigned short u16;
typedef __attribute__((ext_vector_type(8))) short short8;
typedef __attribute__((ext_vector_type(4))) float floatx4;

__device__ __forceinline__ u16 f2bf(float f) {
    union { float f; unsigned u; } in; in.f = f;
    unsigned u = in.u;
    u += 0x7FFFu + ((u >> 16) & 1u);   // RNE
    return (u16)(u >> 16);
}

__device__ __forceinline__ void gl2lds16(const void* g, void* l) {
    __builtin_amdgcn_global_load_lds(
        (const __attribute__((address_space(1))) void*)g,
        (__attribute__((address_space(3))) void*)l, 16, 0, 0);
}

// ---------------- MFMA GEMM, tile 128x64, 4 waves ----------------
// C[M,N] = A[M,K]*B[N,K]^T, bf16 in, staging via global_load_lds.
// EPI 0: f32 store. 1: atomic segment-sum via index[m]. 2: +bias,leaky,bf16.
// 3: +bias,softplus,f32. 4: dual store f32 C + bf16 Cb.
template<int EPI>
__global__ __launch_bounds__(256) void gemm_bf16_64(
    const u16* __restrict__ A, int lda,
    const u16* __restrict__ B, int ldb,
    void* __restrict__ Cout, int ldc, int K,
    const float* __restrict__ bias,
    const int* __restrict__ index,
    u16* __restrict__ Cb)
{
    __shared__ __align__(16) u16 As[128 * 32];
    __shared__ __align__(16) u16 Bs[64 * 32];
    const int tid  = threadIdx.x;
    const int lane = tid & 63;
    const int wave = tid >> 6;
    const int m0 = blockIdx.y * 128, n0 = blockIdx.x * 64;
    const int row = tid >> 2;
    const int kk8 = (tid & 3) * 8;

    const u16* pa0 = A + (size_t)(m0 + row) * lda + kk8;
    const u16* pa1 = pa0 + (size_t)64 * lda;
    const u16* pb  = B + (size_t)(n0 + row) * ldb + kk8;
    u16* la0 = As + wave * 512;
    u16* la1 = As + 2048 + wave * 512;
    u16* lb  = Bs + wave * 512;

    floatx4 acc[2][4] = {};
    const int r16 = lane & 15, kh = lane >> 4;

    for (int k0 = 0; k0 < K; k0 += 32) {
        gl2lds16(pa0 + k0, la0);
        gl2lds16(pa1 + k0, la1);
        gl2lds16(pb + k0, lb);
        __syncthreads();
        short8 af[2], bfr[4];
        #pragma unroll
        for (int i = 0; i < 2; i++)
            af[i] = *(const short8*)(As + (wave * 32 + i * 16 + r16) * 32 + kh * 8);
        #pragma unroll
        for (int j = 0; j < 4; j++)
            bfr[j] = *(const short8*)(Bs + (j * 16 + r16) * 32 + kh * 8);
        #pragma unroll
        for (int i = 0; i < 2; i++)
            #pragma unroll
            for (int j = 0; j < 4; j++)
                acc[i][j] = __builtin_amdgcn_mfma_f32_16x16x32_bf16(af[i], bfr[j], acc[i][j], 0, 0, 0);
        __syncthreads();
    }

    #pragma unroll
    for (int i = 0; i < 2; i++) {
        #pragma unroll
        for (int r = 0; r < 4; r++) {
            const int m = m0 + wave * 32 + i * 16 + kh * 4 + r;
            #pragma unroll
            for (int j = 0; j < 4; j++) {
                const int n = n0 + j * 16 + r16;
                float v = acc[i][j][r];
                if (EPI == 0) {
                    ((float*)Cout)[(size_t)m * ldc + n] = v;
                } else if (EPI == 1) {
                    atomicAdd(&((float*)Cout)[(size_t)index[m] * ldc + n], v);
                } else if (EPI == 2) {
                    v += bias[n];
                    v = (v >= 0.f) ? v : 0.01f * v;
                    ((u16*)Cout)[(size_t)m * ldc + n] = f2bf(v);
                } else if (EPI == 3) {
                    v += bias[n];
                    float sp = (v > 0.f) ? (v + log1pf(__expf(-v))) : log1pf(__expf(v));
                    ((float*)Cout)[(size_t)m * ldc + n] = sp;
                } else {
                    ((float*)Cout)[(size_t)m * ldc + n] = v;
                    Cb[(size_t)m * ldc + n] = f2bf(v);
                }
            }
        }
    }
}

// ---------------- MFMA GEMM, tile 128x128, 4 waves (for gemm2) ----------------
__global__ __launch_bounds__(256) void gemm_bf16_128(
    const u16* __restrict__ A, int lda,
    const u16* __restrict__ B, int ldb,
    float* __restrict__ C, int ldc, int K)
{
    __shared__ __align__(16) u16 As[128 * 32];
    __shared__ __align__(16) u16 Bs[128 * 32];
    const int tid  = threadIdx.x;
    const int lane = tid & 63;
    const int wave = tid >> 6;
    const int m0 = blockIdx.y * 128, n0 = blockIdx.x * 128;
    const int wm = (wave >> 1) * 64, wn = (wave & 1) * 64;
    const int ar0 = tid >> 2;
    const int ak  = (tid & 3) * 8;

    const u16* pa0 = A + (size_t)(m0 + ar0) * lda + ak;
    const u16* pa1 = pa0 + (size_t)64 * lda;
    const u16* pb0 = B + (size_t)(n0 + ar0) * ldb + ak;
    const u16* pb1 = pb0 + (size_t)64 * ldb;
    u16* la0 = As + wave * 512;
    u16* la1 = As + 2048 + wave * 512;
    u16* lb0 = Bs + wave * 512;
    u16* lb1 = Bs + 2048 + wave * 512;

    floatx4 acc[4][4] = {};
    const int r16 = lane & 15, kh = lane >> 4;

    for (int k0 = 0; k0 < K; k0 += 32) {
        gl2lds16(pa0 + k0, la0);
        gl2lds16(pa1 + k0, la1);
        gl2lds16(pb0 + k0, lb0);
        gl2lds16(pb1 + k0, lb1);
        __syncthreads();
        short8 af[4], bfr[4];
        #pragma unroll
        for (int i = 0; i < 4; i++) {
            af[i]  = *(const short8*)(As + (wm + i * 16 + r16) * 32 + kh * 8);
            bfr[i] = *(const short8*)(Bs + (wn + i * 16 + r16) * 32 + kh * 8);
        }
        #pragma unroll
        for (int i = 0; i < 4; i++)
            #pragma unroll
            for (int j = 0; j < 4; j++)
                acc[i][j] = __builtin_amdgcn_mfma_f32_16x16x32_bf16(af[i], bfr[j], acc[i][j], 0, 0, 0);
        __syncthreads();
    }

    #pragma unroll
    for (int i = 0; i < 4; i++)
        #pragma unroll
        for (int r = 0; r < 4; r++) {
            const int m = m0 + wm + i * 16 + kh * 4 + r;
            #pragma unroll
            for (int j = 0; j < 4; j++)
                C[(size_t)m * ldc + n0 + wn + j * 16 + r16] = acc[i][j][r];
        }
}

// cast q/kv/ke into concatenated bf16 catA [L,1536]
__global__ __launch_bounds__(256) void cast_cat_kernel(
    const float* __restrict__ q, const float* __restrict__ kv, const float* __restrict__ ke,
    u16* __restrict__ catA)
{
    const int src = blockIdx.y;
    const float* s = (src == 0) ? q : ((src == 1) ? kv : ke);
    const int i = blockIdx.x * 256 + threadIdx.x;
    const int t = i >> 7;
    const int c = (i & 127) << 2;
    const float4 v = ((const float4*)s)[i];
    ushort4 u;
    u.x = f2bf(v.x); u.y = f2bf(v.y); u.z = f2bf(v.z); u.w = f2bf(v.w);
    *(ushort4*)(catA + (size_t)t * 1536 + src * 512 + c) = u;
}

// fused bf16 cast of the 5 weight matrices (indices in float4 quads)
#define WW_Q 196608  // 512*1536/4
#define IP_Q 131072  // 1024*512/4
#define OP_Q 65536   // 512*512/4
#define XP_Q 8192    // 64*512/4
#define DT_Q 4096    // 512*32/4
__global__ __launch_bounds__(256) void cast_weights_kernel(
    const float* __restrict__ ww, const float* __restrict__ ip,
    const float* __restrict__ op, const float* __restrict__ xp,
    const float* __restrict__ dtw,
    u16* __restrict__ wwb, u16* __restrict__ ipb,
    u16* __restrict__ opb, u16* __restrict__ xpb,
    u16* __restrict__ dtwb)
{
    int i = blockIdx.x * 256 + threadIdx.x;
    const float* s; u16* d;
    if (i < WW_Q)                         { s = ww;  d = wwb; }
    else if ((i -= WW_Q) < IP_Q)          { s = ip;  d = ipb; }
    else if ((i -= IP_Q) < OP_Q)          { s = op;  d = opb; }
    else if ((i -= OP_Q) < XP_Q)          { s = xp;  d = xpb; }
    else if ((i -= XP_Q) < DT_Q)          { s = dtw; d = dtwb; }
    else return;
    const float4 v = ((const float4*)s)[i];
    ushort4 u;
    u.x = f2bf(v.x); u.y = f2bf(v.y); u.z = f2bf(v.z); u.w = f2bf(v.w);
    ((ushort4*)d)[i] = u;
}

// xc = silu(segconv(xz[:, :512])); dual f32 + bf16
__global__ __launch_bounds__(256) void conv_kernel(
    const float* __restrict__ xz,
    const float* __restrict__ conv_w,
    const float* __restrict__ conv_b,
    const int* __restrict__ eb,
    float* __restrict__ xc,
    u16* __restrict__ xcb)
{
    const int t = blockIdx.y;
    const int c = blockIdx.x * blockDim.x + threadIdx.x;
    const int ebt = eb[t];
    float acc = conv_b[c];
    #pragma unroll
    for (int k = 0; k < 4; k++) {
        const int j = t + k - 3;
        if (j >= 0 && eb[j] == ebt)
            acc += conv_w[c * 4 + k] * xz[(size_t)j * 1024 + c];
    }
    const float v = acc / (1.f + __expf(-acc));
    xc[(size_t)t * E_DIM + c] = v;
    xcb[(size_t)t * E_DIM + c] = f2bf(v);
}

// ---------------- Chunked parallel selective scan (3 passes + group combine) ----------------
// stats layout: [k][s][c], strand = s*512+c.

// Pass 1: per-chunk local scan from h=0 -> (aprod, h_end). grid (NCHUNK, 2) x 256.
__global__ __launch_bounds__(256) void scan_chunk_local(
    const float* __restrict__ delta,
    const float* __restrict__ xc,
    const float* __restrict__ dbc,
    const float* __restrict__ A_log,
    const int* __restrict__ eb,
    float* __restrict__ stats_a,
    float* __restrict__ stats_h)
{
    const int k = blockIdx.x;
    const int c = blockIdx.y * 256 + threadIdx.x;
    const int t0 = k * QCHUNK;

    float Areg[NSTATE];
    #pragma unroll
    for (int s = 0; s < NSTATE; s++) Areg[s] = -__expf(A_log[c * NSTATE + s]);
    float h[NSTATE], ap[NSTATE];
    #pragma unroll
    for (int s = 0; s < NSTATE; s++) { h[s] = 0.f; ap[s] = 1.f; }

    float dl = delta[(size_t)t0 * E_DIM + c];
    float xv = xc[(size_t)t0 * E_DIM + c];
    #pragma unroll
    for (int tt = 0; tt < QCHUNK; tt++) {
        const int t = t0 + tt;
        const float* bc = dbc + (size_t)t * 64 + 32;      // wave-uniform -> scalar loads
        const bool f = (t == 0) || (eb[t] != eb[t - 1]);  // wave-uniform
        float dl_n = 0.f, xv_n = 0.f;
        if (tt < QCHUNK - 1) {
            dl_n = delta[(size_t)(t + 1) * E_DIM + c];
            xv_n = xc[(size_t)(t + 1) * E_DIM + c];
        }
        const float dx = dl * xv;
        #pragma unroll
        for (int s = 0; s < NSTATE; s++) {
            const float a = f ? 0.f : __expf(dl * Areg[s]);
            ap[s] *= a;
            h[s] = a * h[s] + dx * bc[s];
        }
        dl = dl_n; xv = xv_n;
    }
    #pragma unroll
    for (int s = 0; s < NSTATE; s++) {
        const size_t o = ((size_t)k * NSTATE + s) * E_DIM + c;
        stats_a[o] = ap[s];
        stats_h[o] = h[s];
    }
}

// Pass 2a: within-group exclusive prefixes, in place; emit group totals.
// grid (NGROUP, 32) x 256.
__global__ __launch_bounds__(256) void scan_comb_a(
    float* __restrict__ stats_a,   // in: aprod -> out: cumA (exclusive, within group)
    float* __restrict__ stats_h,   // in: h_end -> out: h local prefix (exclusive)
    float* __restrict__ gA, float* __restrict__ gH)
{
    const int g = blockIdx.x;
    const int strand = blockIdx.y * 256 + threadIdx.x;
    float cA = 1.f, hh = 0.f;
    for (int kk = 0; kk < GROUP; kk++) {
        const size_t o = (size_t)(g * GROUP + kk) * 8192 + strand;
        const float a  = stats_a[o];
        const float hs = stats_h[o];
        stats_a[o] = cA;
        stats_h[o] = hh;
        cA *= a;
        hh = a * hh + hs;
    }
    const size_t og = (size_t)g * 8192 + strand;
    gA[og] = cA;
    gH[og] = hh;
}

// Pass 2b: sequential scan over 16 group totals. grid 32 x 256.
__global__ __launch_bounds__(256) void scan_comb_b(
    const float* __restrict__ gA, const float* __restrict__ gH,
    float* __restrict__ Hg)
{
    const int strand = blockIdx.x * 256 + threadIdx.x;
    float hh = 0.f;
    #pragma unroll
    for (int g = 0; g < NGROUP; g++) {
        const size_t o = (size_t)g * 8192 + strand;
        Hg[o] = hh;
        hh = gA[o] * hh + gH[o];
    }
}

// Pass 3: re-scan seeded with h = h_local + cumA * Hg, emit gated y (bf16).
__global__ __launch_bounds__(256) void scan_chunk_final(
    const float* __restrict__ delta,
    const float* __restrict__ xc,
    const float* __restrict__ xz,
    const float* __restrict__ dbc,
    const float* __restrict__ A_log,
    const float* __restrict__ Dp,
    const int* __restrict__ eb,
    const float* __restrict__ stats_a,
    const float* __restrict__ stats_h,
    const float* __restrict__ Hg,
    u16* __restrict__ yb)
{
    const int k = blockIdx.x;
    const int c = blockIdx.y * 256 + threadIdx.x;
    const int t0 = k * QCHUNK;
    const int g = k / GROUP;

    float Areg[NSTATE];
    #pragma unroll
    for (int s = 0; s < NSTATE; s++) Areg[s] = -__expf(A_log[c * NSTATE + s]);
    const float Dc = Dp[c];
    float h[NSTATE];
    #pragma unroll
    for (int s = 0; s < NSTATE; s++) {
        const size_t o = ((size_t)k * NSTATE + s) * E_DIM + c;
        h[s] = stats_h[o] + stats_a[o] * Hg[(size_t)g * 8192 + s * E_DIM + c];
    }

    float dl = delta[(size_t)t0 * E_DIM + c];
    float xv = xc[(size_t)t0 * E_DIM + c];
    float zv = xz[(size_t)t0 * 1024 + 512 + c];
    #pragma unroll
    for (int tt = 0; tt < QCHUNK; tt++) {
        const int t = t0 + tt;
        const float* bc = dbc + (size_t)t * 64 + 32;
        const bool f = (t == 0) || (eb[t] != eb[t - 1]);
        float dl_n = 0.f, xv_n = 0.f, zv_n = 0.f;
        if (tt < QCHUNK - 1) {
            dl_n = delta[(size_t)(t + 1) * E_DIM + c];
            xv_n = xc[(size_t)(t + 1) * E_DIM + c];
            zv_n = xz[(size_t)(t + 1) * 1024 + 512 + c];
        }
        const float dx = dl * xv;
        float sum = 0.f;
        #pragma unroll
        for (int s = 0; s < NSTATE; s++) {
            const float a = f ? 0.f : __expf(dl * Areg[s]);
            h[s] = a * h[s] + dx * bc[s];
            sum += h[s] * bc[16 + s];
        }
        const float yv = sum + Dc * xv;
        const float zs = zv / (1.f + __expf(-zv));
        yb[(size_t)t * E_DIM + c] = f2bf(yv * zs);
        dl = dl_n; xv = xv_n; zv = zv_n;
    }
}

extern "C" void kernel_launch(void* const* d_in, const int* in_sizes, int n_in,
                              void* d_out, int out_size, void* d_ws, size_t ws_size,
                              hipStream_t stream) {
    const float* q          = (const float*)d_in[0];
    const float* kv         = (const float*)d_in[1];
    const float* ke         = (const float*)d_in[2];
    const int*   index      = (const int*)d_in[3];
    const int*   eb         = (const int*)d_in[5];
    const float* w_weight   = (const float*)d_in[6];
    const float* w_bias     = (const float*)d_in[7];
    const float* in_proj_w  = (const float*)d_in[8];
    const float* conv_w     = (const float*)d_in[9];
    const float* conv_b     = (const float*)d_in[10];
    const float* x_proj_w   = (const float*)d_in[11];
    const float* dt_proj_w  = (const float*)d_in[12];
    const float* dt_proj_b  = (const float*)d_in[13];
    const float* A_log      = (const float*)d_in[14];
    const float* Dp         = (const float*)d_in[15];
    const float* out_proj_w = (const float*)d_in[16];
    float* out = (float*)d_out;

    // Flat workspace, no aliasing. Total ~153 MB; ws_size = 256 MiB
    // (evidence: harness d_ws poison fill writes exactly 262144 KB).
    float* p = (float*)d_ws;
    float* xz      = p; p += (size_t)L_SEQ * 1024;          // 32 MB
    float* xc      = p; p += (size_t)L_SEQ * 512;           // 16 MB
    float* dbc     = p; p += (size_t)L_SEQ * 64;            // 2 MB
    float* delta   = p; p += (size_t)L_SEQ * 512;           // 16 MB
    float* stats_a = p; p += (size_t)NCHUNK * 8192;         // 16 MB
    float* stats_h = p; p += (size_t)NCHUNK * 8192;         // 16 MB
    float* gA      = p; p += (size_t)NGROUP * 8192;         // 0.5 MB
    float* gH      = p; p += (size_t)NGROUP * 8192;         // 0.5 MB
    float* Hg      = p; p += (size_t)NGROUP * 8192;         // 0.5 MB
    u16* catA = (u16*)p;  p += (size_t)L_SEQ * 1536 / 2;    // 24 MB
    u16* xbf  = (u16*)p;  p += (size_t)L_SEQ * 512 / 2;     // 8 MB
    u16* xcb  = (u16*)p;  p += (size_t)L_SEQ * 512 / 2;     // 8 MB
    u16* ybf  = (u16*)p;  p += (size_t)L_SEQ * 512 / 2;     // 8 MB
    u16* dbcb = (u16*)p;  p += (size_t)L_SEQ * 64 / 2;      // 1 MB
    u16* wwb  = (u16*)p;  p += (size_t)512 * 1536 / 2;
    u16* ipb  = (u16*)p;  p += (size_t)1024 * 512 / 2;
    u16* opb  = (u16*)p;  p += (size_t)512 * 512 / 2;
    u16* xpb  = (u16*)p;  p += (size_t)64 * 512 / 2;
    u16* dtwb = (u16*)p;  p += (size_t)512 * 32 / 2;

    hipMemsetAsync(d_out, 0, (size_t)out_size * sizeof(float), stream);

    // casts (2 kernels)
    cast_cat_kernel<<<dim3(L_SEQ * 512 / 1024, 3), dim3(256), 0, stream>>>(q, kv, ke, catA);
    cast_weights_kernel<<<dim3((WW_Q + IP_Q + OP_Q + XP_Q + DT_Q + 255) / 256), dim3(256), 0, stream>>>(
        w_weight, in_proj_w, out_proj_w, x_proj_w, dt_proj_w, wwb, ipb, opb, xpb, dtwb);

    // 1) xbf = leaky(catA @ wwb^T + w_bias)  grid (8,64) = 512 blocks
    gemm_bf16_64<2><<<dim3(8, 64), dim3(256), 0, stream>>>(
        catA, 1536, wwb, 1536, xbf, 512, 1536, w_bias, nullptr, nullptr);
    // 2) xz = xbf @ ipb^T  (f32, Lx1024), 128x128 tile, grid (8,64)
    gemm_bf16_128<<<dim3(8, 64), dim3(256), 0, stream>>>(
        xbf, 512, ipb, 512, xz, 1024, 512);
    // 3) xc, xcb = silu(segconv(xz[:, :512]))
    conv_kernel<<<dim3(2, L_SEQ), dim3(256), 0, stream>>>(xz, conv_w, conv_b, eb, xc, xcb);
    // 4) dbc (f32) + dbcb (bf16) = xcb @ xpb^T, grid (1,64)
    gemm_bf16_64<4><<<dim3(1, 64), dim3(256), 0, stream>>>(
        xcb, 512, xpb, 512, dbc, 64, 512, nullptr, nullptr, dbcb);
    // 5) delta = softplus(dbcb[:, :32] @ dtwb^T + dt_proj_b)  (MFMA, K=32), grid (8,64)
    gemm_bf16_64<3><<<dim3(8, 64), dim3(256), 0, stream>>>(
        dbcb, 64, dtwb, 32, delta, 512, 32, dt_proj_b, nullptr, nullptr);
    // 6) scan
    scan_chunk_local<<<dim3(NCHUNK, 2), dim3(256), 0, stream>>>(
        delta, xc, dbc, A_log, eb, stats_a, stats_h);
    scan_comb_a<<<dim3(NGROUP, 32), dim3(256), 0, stream>>>(stats_a, stats_h, gA, gH);
    scan_comb_b<<<dim3(32), dim3(256), 0, stream>>>(gA, gH, Hg);
    scan_chunk_final<<<dim3(NCHUNK, 2), dim3(256), 0, stream>>>(
        delta, xc, xz, dbc, A_log, Dp, eb, stats_a, stats_h, Hg, ybf);
    // 7) out += segment_sum(ybf @ opb^T), grid (8,64)
    gemm_bf16_64<1><<<dim3(8, 64), dim3(256), 0, stream>>>(
        ybf, 512, opb, 512, out, 512, 512, nullptr, index, nullptr);
}